// Round 17
// baseline (310.295 us; speedup 1.0000x reference)
//
#include <hip/hip_runtime.h>
#include <hip/hip_bf16.h>

typedef __attribute__((ext_vector_type(8))) short bf16x8;
typedef __attribute__((ext_vector_type(4))) short bf16x4;
typedef __attribute__((ext_vector_type(4))) float f32x4;

#define NTOK 8192
#define SEQ  1024
#define NH   8

__device__ __forceinline__ float bfs2f(short s) {
  union { unsigned u; float f; } x; x.u = ((unsigned)(unsigned short)s) << 16; return x.f;
}
__device__ __forceinline__ short f2bfs(float f) {
  __hip_bfloat16 h = __float2bfloat16(f);
  return *reinterpret_cast<short*>(&h);
}
__device__ __forceinline__ float bfp2f(const __hip_bfloat16* p) {
  return bfs2f(*reinterpret_cast<const short*>(p));
}

__device__ __forceinline__ void gld16(const void* g, void* l) {
  __builtin_amdgcn_global_load_lds(
      (__attribute__((address_space(1))) void*)const_cast<void*>(g),
      (__attribute__((address_space(3))) void*)l, 16, 0, 0);
}

// ---------------- fused f32 weight -> bf16 cast (all big tensors, 1 launch) ------
struct WSeg { const float* src; unsigned dst_off; unsigned nvec; };
struct WPack { WSeg s[8]; };

__global__ __launch_bounds__(256) void cast_wall_kernel(WPack p,
                                                        __hip_bfloat16* __restrict__ dst) {
  unsigned v = blockIdx.x * 256 + threadIdx.x;
#pragma unroll
  for (int t = 0; t < 8; ++t) {
    if (v < p.s[t].nvec) {
      const float* s = p.s[t].src + (size_t)v * 8;
      f32x4 a = *reinterpret_cast<const f32x4*>(s);
      f32x4 b = *reinterpret_cast<const f32x4*>(s + 4);
      bf16x8 o;
#pragma unroll
      for (int j = 0; j < 4; ++j) { o[j] = f2bfs(a[j]); o[4 + j] = f2bfs(b[j]); }
      *reinterpret_cast<bf16x8*>(reinterpret_cast<short*>(dst) +
                                 (size_t)(p.s[t].dst_off + v) * 8) = o;
      return;
    }
    v -= p.s[t].nvec;
  }
}

// ---------------- dw_w f32 [512][31] -> bf16 transposed [31][512] ----------------
__global__ __launch_bounds__(256) void cast_dww_kernel(const float* __restrict__ src,
                                                       __hip_bfloat16* __restrict__ dst) {
  for (int k = 0; k < 31; ++k)
    for (int c = threadIdx.x; c < 512; c += 256)
      dst[k * 512 + c] = __float2bfloat16(src[c * 31 + k]);
}

struct PtrPack { const void* p[23]; };

__global__ __launch_bounds__(256) void cast_small_kernel(PtrPack pk,
                                                         __hip_bfloat16* __restrict__ dst) {
  constexpr int sizes[23] = {512, 512, 2048, 512, 512, 512, 1536, 512, 512, 512, 1024, 512,
                             512, 512, 512, 512, 512, 512, 512, 2048, 512, 512, 512};
  int off = 0;
  for (int t = 0; t < 23; ++t) {
    const int n = sizes[t];
    for (int i = threadIdx.x; i < n; i += 256)
      dst[off + i] = __float2bfloat16(((const float*)pk.p[t])[i]);
    off += n;
  }
}

__global__ void ws_bad_kernel(float* __restrict__ out) {
  if (threadIdx.x == 0) out[0] = 5000.f;
}

// ---------------- LayerNorm: fp32 in -> bf16 out (D=512) ----------------
__global__ __launch_bounds__(256) void ln_kernel(const float* __restrict__ in,
                                                 const __hip_bfloat16* __restrict__ g,
                                                 const __hip_bfloat16* __restrict__ b,
                                                 __hip_bfloat16* __restrict__ out) {
  const int wv = threadIdx.x >> 6, ln = threadIdx.x & 63;
  const int row = blockIdx.x * 4 + wv;
  const float* p = in + (size_t)row * 512 + ln * 8;
  float v[8];
  {
    const f32x4* p4 = reinterpret_cast<const f32x4*>(p);
    f32x4 a = p4[0], c = p4[1];
#pragma unroll
    for (int j = 0; j < 4; ++j) { v[j] = a[j]; v[4 + j] = c[j]; }
  }
  float s = 0.f;
#pragma unroll
  for (int j = 0; j < 8; ++j) s += v[j];
  for (int m = 1; m < 64; m <<= 1) s += __shfl_xor(s, m);
  const float mean = s * (1.f / 512.f);
  float q = 0.f;
#pragma unroll
  for (int j = 0; j < 8; ++j) { float d = v[j] - mean; q += d * d; }
  for (int m = 1; m < 64; m <<= 1) q += __shfl_xor(q, m);
  const float rstd = rsqrtf(q * (1.f / 512.f) + 1e-5f);
  bf16x8 gg = *reinterpret_cast<const bf16x8*>(g + ln * 8);
  bf16x8 bb = *reinterpret_cast<const bf16x8*>(b + ln * 8);
  bf16x8 ov;
#pragma unroll
  for (int j = 0; j < 8; ++j)
    ov[j] = f2bfs((v[j] - mean) * rstd * bfs2f(gg[j]) + bfs2f(bb[j]));
  *reinterpret_cast<bf16x8*>(out + (size_t)row * 512 + ln * 8) = ov;
}

// ---------------- final LayerNorm: fp32 in -> FP32 out ----------------
__global__ __launch_bounds__(256) void lnf_kernel(const float* __restrict__ in,
                                                  const __hip_bfloat16* __restrict__ g,
                                                  const __hip_bfloat16* __restrict__ b,
                                                  float* __restrict__ out) {
  const int wv = threadIdx.x >> 6, ln = threadIdx.x & 63;
  const int row = blockIdx.x * 4 + wv;
  const float* p = in + (size_t)row * 512 + ln * 8;
  float v[8];
  {
    const f32x4* p4 = reinterpret_cast<const f32x4*>(p);
    f32x4 a = p4[0], c = p4[1];
#pragma unroll
    for (int j = 0; j < 4; ++j) { v[j] = a[j]; v[4 + j] = c[j]; }
  }
  float s = 0.f;
#pragma unroll
  for (int j = 0; j < 8; ++j) s += v[j];
  for (int m = 1; m < 64; m <<= 1) s += __shfl_xor(s, m);
  const float mean = s * (1.f / 512.f);
  float q = 0.f;
#pragma unroll
  for (int j = 0; j < 8; ++j) { float d = v[j] - mean; q += d * d; }
  for (int m = 1; m < 64; m <<= 1) q += __shfl_xor(q, m);
  const float rstd = rsqrtf(q * (1.f / 512.f) + 1e-5f);
  bf16x8 gg = *reinterpret_cast<const bf16x8*>(g + ln * 8);
  bf16x8 bb = *reinterpret_cast<const bf16x8*>(b + ln * 8);
  f32x4 o0, o1;
#pragma unroll
  for (int j = 0; j < 4; ++j) {
    o0[j] = (v[j] - mean) * rstd * bfs2f(gg[j]) + bfs2f(bb[j]);
    o1[j] = (v[4 + j] - mean) * rstd * bfs2f(gg[4 + j]) + bfs2f(bb[4 + j]);
  }
  float* op = out + (size_t)row * 512 + ln * 8;
  *reinterpret_cast<f32x4*>(op) = o0;
  *reinterpret_cast<f32x4*>(op + 4) = o1;
}

// ======== 8-phase-family GEMM: BM=BN=256, BK=32, 4-deep LDS pipeline =============
// For M=2048, K=512 silu GEMMs. 512 threads (8 waves, 2Mx4N), 1 block/CU.
// T3+T4: staging runs 2 K-tiles ahead of compute across 4 LDS buffers; the
// per-K-tile gate is a COUNTED s_waitcnt vmcnt(6) (1 pre-gate stage + 4 loads of
// kt+1 stay in flight) + ONE raw s_barrier. T5 setprio around MFMA clusters.
// Swizzle: granule g ^ ((row>>1)&3) on both stage-source and LDS-read (2-way
// bank aliasing = free). Same math order as gemm_bt -> bit-identical output.
__global__ __launch_bounds__(512, 2) void gemm8p_silu(const __hip_bfloat16* __restrict__ A,
                                                      const __hip_bfloat16* __restrict__ W,
                                                      const __hip_bfloat16* __restrict__ bias,
                                                      __hip_bfloat16* __restrict__ outb,
                                                      int K, int M) {
  __shared__ __align__(16) short LA[4][256 * 32];
  __shared__ __align__(16) short LB[4][256 * 32];
  const int tid = threadIdx.x;
  const int wid = tid >> 6, ln = tid & 63;
  const int hi = ln >> 4, lo = ln & 15;
  const int wr = wid >> 2, wn = wid & 3;
  // XCD chunked swizzle: grid 32 x (M/256); nwg % 8 == 0.
  const int gx = gridDim.x;                      // 32
  const int nwg = gx * gridDim.y;
  const int t = blockIdx.y * gx + blockIdx.x;
  const int w = (t & 7) * (nwg >> 3) + (t >> 3);
  const int n0 = (w & (gx - 1)) * 256;
  const int m0 = (w / gx) * 256;

  // staging lane geometry: row-in-half r = tid>>2, slot = tid&3,
  // swizzled source granule = slot ^ ((r>>1)&3)
  const int srow = tid >> 2;                     // 0..127
  const int sg = (tid & 3) ^ ((tid >> 3) & 3);   // swizzled global granule
  const int rswz = (lo >> 1) & 3;                // read-side row-swizzle term

  f32x4 acc[8][4] = {};

  const int NKT = K >> 5;                        // 16 K-tiles of 32

  // prologue: stage K-tiles 0 and 1 (A halves then B halves each)
#pragma unroll
  for (int kt = 0; kt < 2; ++kt) {
#pragma unroll
    for (int h = 0; h < 2; ++h)
      gld16(A + (size_t)(n0 + h * 128 + srow) * K + kt * 32 + sg * 8,
            &LA[kt][h * 4096 + wid * 512]);
#pragma unroll
    for (int h = 0; h < 2; ++h)
      gld16(W + (size_t)(m0 + h * 128 + srow) * K + kt * 32 + sg * 8,
            &LB[kt][h * 4096 + wid * 512]);
  }

  for (int kt = 0; kt < NKT; ++kt) {
    const int d = kt & 3;
    const int dn = (kt + 2) & 3;
    // pre-gate stage: A halves of kt+2
    if (kt < NKT - 2) {
#pragma unroll
      for (int h = 0; h < 2; ++h)
        gld16(A + (size_t)(n0 + h * 128 + srow) * K + (kt + 2) * 32 + sg * 8,
              &LA[dn][h * 4096 + wid * 512]);
    }
    // gate: wait for kt's 4 loads (issued 2 iters ago); keep newer in flight
    if (kt < NKT - 2)      asm volatile("s_waitcnt vmcnt(6)" ::: "memory");
    else if (kt == NKT - 2) asm volatile("s_waitcnt vmcnt(4)" ::: "memory");
    else                    asm volatile("s_waitcnt vmcnt(0)" ::: "memory");
    __builtin_amdgcn_sched_barrier(0);
    asm volatile("" ::: "memory");
    __builtin_amdgcn_s_barrier();    // all threads gated -> kt's tile visible
    asm volatile("" ::: "memory");
    __builtin_amdgcn_sched_barrier(0);

    // B fragments for this K-tile (held across both phases)
    bf16x8 bfr[4];
#pragma unroll
    for (int nf = 0; nf < 4; ++nf) {
      const int row = wn * 64 + nf * 16 + lo;
      bfr[nf] = *reinterpret_cast<const bf16x8*>(&LB[d][row * 32 + ((hi ^ rswz) << 3)]);
    }

    // phase 0: M-frags 0..3
    {
      bf16x8 af[4];
#pragma unroll
      for (int mf = 0; mf < 4; ++mf) {
        const int row = wr * 128 + mf * 16 + lo;
        af[mf] = *reinterpret_cast<const bf16x8*>(&LA[d][row * 32 + ((hi ^ rswz) << 3)]);
      }
      __builtin_amdgcn_s_setprio(1);
#pragma unroll
      for (int mf = 0; mf < 4; ++mf)
#pragma unroll
        for (int nf = 0; nf < 4; ++nf)
          acc[mf][nf] = __builtin_amdgcn_mfma_f32_16x16x32_bf16(af[mf], bfr[nf], acc[mf][nf], 0, 0, 0);
      __builtin_amdgcn_s_setprio(0);
    }

    // mid-iteration stage: B halves of kt+2
    if (kt < NKT - 2) {
#pragma unroll
      for (int h = 0; h < 2; ++h)
        gld16(W + (size_t)(m0 + h * 128 + srow) * K + (kt + 2) * 32 + sg * 8,
              &LB[dn][h * 4096 + wid * 512]);
    }

    // phase 1: M-frags 4..7
    {
      bf16x8 af[4];
#pragma unroll
      for (int mf = 0; mf < 4; ++mf) {
        const int row = wr * 128 + (mf + 4) * 16 + lo;
        af[mf] = *reinterpret_cast<const bf16x8*>(&LA[d][row * 32 + ((hi ^ rswz) << 3)]);
      }
      __builtin_amdgcn_s_setprio(1);
#pragma unroll
      for (int mf = 0; mf < 4; ++mf)
#pragma unroll
        for (int nf = 0; nf < 4; ++nf)
          acc[mf + 4][nf] = __builtin_amdgcn_mfma_f32_16x16x32_bf16(af[mf], bfr[nf], acc[mf + 4][nf], 0, 0, 0);
      __builtin_amdgcn_s_setprio(0);
    }
    __builtin_amdgcn_sched_barrier(0);
  }

  // epilogue: bias + silu + bf16 store
#pragma unroll
  for (int mf = 0; mf < 8; ++mf) {
#pragma unroll
    for (int nf = 0; nf < 4; ++nf) {
      const int m = m0 + wn * 64 + nf * 16 + lo;
      const float bv = bfp2f(bias + m);
#pragma unroll
      for (int j = 0; j < 4; ++j) {
        const int n = n0 + wr * 128 + mf * 16 + hi * 4 + j;
        float v = acc[mf][nf][j] + bv;
        v = v / (1.f + __expf(-v));
        outb[(size_t)n * M + m] = __float2bfloat16(v);
      }
    }
  }
}

// ---------------- MFMA GEMM (m97 + T2 swizzle, XCD-swizzled, 3 blocks/CU) --------
// EPI 0: bf16 out ; EPI 1: bf16 silu ; EPI 2: fp32 resid update ;
// EPI 3: qkv — Q/K to outb, V written TRANSPOSED to vTout[b,h,d,s] (short4).
template <int EPI>
__global__ __launch_bounds__(256, 3) void gemm_bt(const __hip_bfloat16* __restrict__ A,
                                                  const __hip_bfloat16* __restrict__ W,
                                                  const __hip_bfloat16* __restrict__ bias,
                                                  __hip_bfloat16* __restrict__ outb,
                                                  float* __restrict__ resid,
                                                  __hip_bfloat16* __restrict__ vTout,
                                                  int K, int M, float alpha, float beta) {
  __shared__ __align__(16) __hip_bfloat16 As[128 * 64];
  __shared__ __align__(16) __hip_bfloat16 Bs[128 * 64];
  const int tid = threadIdx.x;
  const int wv = tid >> 6, ln = tid & 63;
  const int hi = ln >> 4, lo = ln & 15;
  const int lo7 = lo & 7;
  const int gx = gridDim.x;
  const int nwg = gx * gridDim.y;
  const int t = blockIdx.y * gx + blockIdx.x;
  const int w = (t & 7) * (nwg >> 3) + (t >> 3);
  const int n0 = (w & (gx - 1)) * 128;
  const int m0 = (w / gx) * 128;
  const int wr = wv >> 1, wc = wv & 1;
  const int srow = ln >> 3;
  const int scolz = (((ln & 7) ^ srow) << 3);   // swizzled source granule

  f32x4 acc[4][4] = {};

  for (int k0 = 0; k0 < K; k0 += 64) {
    __syncthreads();
#pragma unroll
    for (int i = 0; i < 4; ++i) {
      const int grp = i * 4 + wv;
      const int row = grp * 8 + srow;
      gld16(A + (size_t)(n0 + row) * K + k0 + scolz, As + grp * 512);
      gld16(W + (size_t)(m0 + row) * K + k0 + scolz, Bs + grp * 512);
    }
    __syncthreads();
#pragma unroll
    for (int kk2 = 0; kk2 < 2; ++kk2) {
      const int g0 = ((kk2 * 4 + hi) ^ lo7) << 3;   // swizzled read granule
      bf16x8 af[4], bfr[4];
#pragma unroll
      for (int r = 0; r < 4; ++r)
        af[r] = *reinterpret_cast<const bf16x8*>(As + (wr * 64 + r * 16 + lo) * 64 + g0);
#pragma unroll
      for (int c = 0; c < 4; ++c)
        bfr[c] = *reinterpret_cast<const bf16x8*>(Bs + (wc * 64 + c * 16 + lo) * 64 + g0);
#pragma unroll
      for (int r = 0; r < 4; ++r)
#pragma unroll
        for (int c = 0; c < 4; ++c)
          acc[r][c] = __builtin_amdgcn_mfma_f32_16x16x32_bf16(af[r], bfr[c], acc[r][c], 0, 0, 0);
    }
  }

#pragma unroll
  for (int r = 0; r < 4; ++r) {
#pragma unroll
    for (int c = 0; c < 4; ++c) {
      const int m = m0 + wc * 64 + c * 16 + lo;
      const float bv = bfp2f(bias + m);
      const int nb = n0 + wr * 64 + r * 16 + hi * 4;
      if constexpr (EPI == 3) {
        if (m >= 1024) {  // V part -> transposed store
          const int hd = m - 1024;
          __hip_bfloat16* vp = vTout +
              ((size_t)((nb >> 10) * NH + (hd >> 6)) * 64 + (hd & 63)) * 1024 + (nb & 1023);
          bf16x4 vv;
#pragma unroll
          for (int j = 0; j < 4; ++j) vv[j] = f2bfs(acc[r][c][j] + bv);
          *reinterpret_cast<bf16x4*>(vp) = vv;
          continue;
        }
      }
#pragma unroll
      for (int j = 0; j < 4; ++j) {
        const int n = nb + j;
        float v = acc[r][c][j] + bv;
        if constexpr (EPI == 1) v = v / (1.f + __expf(-v));
        if constexpr (EPI == 2) {
          const size_t idx = (size_t)n * 512 + m;
          resid[idx] = alpha * resid[idx] + beta * v;
        } else {
          outb[(size_t)n * M + m] = __float2bfloat16(v);
        }
      }
    }
  }
}

// ---------------- MFMA GEMM, M=512 resid: BM=64 x BN=128 + T2 swizzle ------------
__global__ __launch_bounds__(256, 4) void gemm64_resid(const __hip_bfloat16* __restrict__ A,
                                                       const __hip_bfloat16* __restrict__ W,
                                                       const __hip_bfloat16* __restrict__ bias,
                                                       const float* __restrict__ rsrc,
                                                       float* __restrict__ resid,
                                                       int K, float alpha, float beta) {
  __shared__ __align__(16) __hip_bfloat16 As[64 * 64];
  __shared__ __align__(16) __hip_bfloat16 Bs[128 * 64];
  const int tid = threadIdx.x;
  const int wv = tid >> 6, ln = tid & 63;
  const int hi = ln >> 4, lo = ln & 15;
  const int lo7 = lo & 7;
  const int gx = gridDim.x;
  const int nwg = gx * gridDim.y;
  const int t = blockIdx.y * gx + blockIdx.x;
  const int w = (t & 7) * (nwg >> 3) + (t >> 3);
  const int n0 = (w & (gx - 1)) * 64;
  const int m0 = (w / gx) * 128;
  const int wr = wv >> 1, wc = wv & 1;
  const int srow = ln >> 3;
  const int scolz = (((ln & 7) ^ srow) << 3);

  f32x4 acc[2][4] = {};

  for (int k0 = 0; k0 < K; k0 += 64) {
    __syncthreads();
#pragma unroll
    for (int i = 0; i < 2; ++i) {
      const int grp = i * 4 + wv;
      gld16(A + (size_t)(n0 + grp * 8 + srow) * K + k0 + scolz, As + grp * 512);
    }
#pragma unroll
    for (int i = 0; i < 4; ++i) {
      const int grp = i * 4 + wv;
      gld16(W + (size_t)(m0 + grp * 8 + srow) * K + k0 + scolz, Bs + grp * 512);
    }
    __syncthreads();
#pragma unroll
    for (int kk2 = 0; kk2 < 2; ++kk2) {
      const int g0 = ((kk2 * 4 + hi) ^ lo7) << 3;
      bf16x8 af[2], bfr[4];
#pragma unroll
      for (int r = 0; r < 2; ++r)
        af[r] = *reinterpret_cast<const bf16x8*>(As + (wr * 32 + r * 16 + lo) * 64 + g0);
#pragma unroll
      for (int c = 0; c < 4; ++c)
        bfr[c] = *reinterpret_cast<const bf16x8*>(Bs + (wc * 64 + c * 16 + lo) * 64 + g0);
#pragma unroll
      for (int r = 0; r < 2; ++r)
#pragma unroll
        for (int c = 0; c < 4; ++c)
          acc[r][c] = __builtin_amdgcn_mfma_f32_16x16x32_bf16(af[r], bfr[c], acc[r][c], 0, 0, 0);
    }
  }

#pragma unroll
  for (int r = 0; r < 2; ++r) {
#pragma unroll
    for (int c = 0; c < 4; ++c) {
      const int m = m0 + wc * 64 + c * 16 + lo;
      const float bv = bfp2f(bias + m);
#pragma unroll
      for (int j = 0; j < 4; ++j) {
        const int n = n0 + wr * 32 + r * 16 + hi * 4 + j;
        const size_t idx = (size_t)n * 512 + m;
        resid[idx] = alpha * rsrc[idx] + beta * (acc[r][c][j] + bv);
      }
    }
  }
}

// ---------------- MFMA flash attention v6: 2 q-tiles/wave, K/V frag reuse --------
__global__ __launch_bounds__(256, 2) void attn_kernel(const __hip_bfloat16* __restrict__ qkv,
                                                      const __hip_bfloat16* __restrict__ vT,
                                                      __hip_bfloat16* __restrict__ ctx) {
  __shared__ __align__(16) short Ks[2][64 * 64];
  __shared__ __align__(16) short Vs[2][64 * 64];
  __shared__ __align__(16) short P[4][16][64];
  const int tid = threadIdx.x;
  const int wv = tid >> 6, ln = tid & 63;
  const int hi = ln >> 4, lo = ln & 15;
  const int lo7 = lo & 7;
  const int blk = ((blockIdx.x & 7) << 6) | (blockIdx.x >> 3);
  const int qt = blk & 7, h = (blk >> 3) & 7, b = blk >> 6;
  const int q0 = qt * 128 + wv * 16;   // tile A rows; tile B = q0 + 64

  const int srow8 = ln >> 3;
  const int gsrc = (ln & 7) ^ srow8;

  bf16x8 aq0a, aq1a, aq0b, aq1b;
  {
    const __hip_bfloat16* qpa = qkv + (size_t)(b * SEQ + q0 + lo) * 1536 + h * 64 + hi * 8;
    const __hip_bfloat16* qpb = qpa + (size_t)64 * 1536;
    bf16x8 r0 = *reinterpret_cast<const bf16x8*>(qpa);
    bf16x8 r1 = *reinterpret_cast<const bf16x8*>(qpa + 32);
    bf16x8 r2 = *reinterpret_cast<const bf16x8*>(qpb);
    bf16x8 r3 = *reinterpret_cast<const bf16x8*>(qpb + 32);
#pragma unroll
    for (int j = 0; j < 8; ++j) {
      aq0a[j] = f2bfs(bfs2f(r0[j]) * 0.125f);
      aq1a[j] = f2bfs(bfs2f(r1[j]) * 0.125f);
      aq0b[j] = f2bfs(bfs2f(r2[j]) * 0.125f);
      aq1b[j] = f2bfs(bfs2f(r3[j]) * 0.125f);
    }
  }

  const __hip_bfloat16* kbase = qkv + 512 + h * 64 + (size_t)b * SEQ * 1536;
  const __hip_bfloat16* vbase = vT + (size_t)(b * NH + h) * 64 * 1024;

  f32x4 oaccA[4] = {}, oaccB[4] = {};
  float lrowA[4] = {0.f, 0.f, 0.f, 0.f};
  float lrowB[4] = {0.f, 0.f, 0.f, 0.f};

#pragma unroll
  for (int c = 0; c < 2; ++c) {
    const int r = c * 32 + wv * 8 + srow8;
    gld16(kbase + (size_t)r * 1536 + gsrc * 8, &Ks[0][(c * 32 + wv * 8) * 64]);
    gld16(vbase + (size_t)r * 1024 + gsrc * 8, &Vs[0][(c * 32 + wv * 8) * 64]);
  }
  __syncthreads();

  int cb = 0;
  for (int kt = 0; kt < 16; ++kt) {
    if (kt < 15) {
      const int kb2 = (kt + 1) * 64;
#pragma unroll
      for (int c = 0; c < 2; ++c) {
        const int r = c * 32 + wv * 8 + srow8;
        gld16(kbase + (size_t)(kb2 + r) * 1536 + gsrc * 8,
              &Ks[cb ^ 1][(c * 32 + wv * 8) * 64]);
        gld16(vbase + (size_t)r * 1024 + kb2 + gsrc * 8,
              &Vs[cb ^ 1][(c * 32 + wv * 8) * 64]);
      }
    }

    bf16x8 bk0[4], bk1[4];
#pragma unroll
    for (int nt = 0; nt < 4; ++nt) {
      const short* kr = &Ks[cb][(nt * 16 + lo) * 64];
      bk0[nt] = *reinterpret_cast<const bf16x8*>(kr + ((hi ^ lo7) << 3));
      bk1[nt] = *reinterpret_cast<const bf16x8*>(kr + (((hi + 4) ^ lo7) << 3));
    }
    f32x4 scA[4] = {}, scB[4] = {};
#pragma unroll
    for (int nt = 0; nt < 4; ++nt) {
      scA[nt] = __builtin_amdgcn_mfma_f32_16x16x32_bf16(aq0a, bk0[nt], scA[nt], 0, 0, 0);
      scA[nt] = __builtin_amdgcn_mfma_f32_16x16x32_bf16(aq1a, bk1[nt], scA[nt], 0, 0, 0);
      scB[nt] = __builtin_amdgcn_mfma_f32_16x16x32_bf16(aq0b, bk0[nt], scB[nt], 0, 0, 0);
      scB[nt] = __builtin_amdgcn_mfma_f32_16x16x32_bf16(aq1b, bk1[nt], scB[nt], 0, 0, 0);
    }

    bf16x8 bv0[4], bv1[4];
#pragma unroll
    for (int dt = 0; dt < 4; ++dt) {
      const short* vr = &Vs[cb][(dt * 16 + lo) * 64];
      bv0[dt] = *reinterpret_cast<const bf16x8*>(vr + ((hi ^ lo7) << 3));
      bv1[dt] = *reinterpret_cast<const bf16x8*>(vr + (((hi + 4) ^ lo7) << 3));
    }

#pragma unroll
    for (int j = 0; j < 4; ++j) {
      const int prow = hi * 4 + j;
      const int pswz = (prow & 7) << 3;
#pragma unroll
      for (int nt = 0; nt < 4; ++nt) {
        const float p = __expf(scA[nt][j]);
        P[wv][prow][(nt * 16 + lo) ^ pswz] = f2bfs(p);
        lrowA[j] += p;
      }
    }
    asm volatile("" ::: "memory");
    {
      const short* pr = &P[wv][lo][0];
      bf16x8 ap0 = *reinterpret_cast<const bf16x8*>(pr + ((hi ^ lo7) << 3));
      bf16x8 ap1 = *reinterpret_cast<const bf16x8*>(pr + (((hi + 4) ^ lo7) << 3));
#pragma unroll
      for (int dt = 0; dt < 4; ++dt) {
        oaccA[dt] = __builtin_amdgcn_mfma_f32_16x16x32_bf16(ap0, bv0[dt], oaccA[dt], 0, 0, 0);
        oaccA[dt] = __builtin_amdgcn_mfma_f32_16x16x32_bf16(ap1, bv1[dt], oaccA[dt], 0, 0, 0);
      }
    }
    asm volatile("" ::: "memory");

#pragma unroll
    for (int j = 0; j < 4; ++j) {
      const int prow = hi * 4 + j;
      const int pswz = (prow & 7) << 3;
#pragma unroll
      for (int nt = 0; nt < 4; ++nt) {
        const float p = __expf(scB[nt][j]);
        P[wv][prow][(nt * 16 + lo) ^ pswz] = f2bfs(p);
        lrowB[j] += p;
      }
    }
    asm volatile("" ::: "memory");
    {
      const short* pr = &P[wv][lo][0];
      bf16x8 ap0 = *reinterpret_cast<const bf16x8*>(pr + ((hi ^ lo7) << 3));
      bf16x8 ap1 = *reinterpret_cast<const bf16x8*>(pr + (((hi + 4) ^ lo7) << 3));
#pragma unroll
      for (int dt = 0; dt < 4; ++dt) {
        oaccB[dt] = __builtin_amdgcn_mfma_f32_16x16x32_bf16(ap0, bv0[dt], oaccB[dt], 0, 0, 0);
        oaccB[dt] = __builtin_amdgcn_mfma_f32_16x16x32_bf16(ap1, bv1[dt], oaccB[dt], 0, 0, 0);
      }
    }
    __syncthreads();
    cb ^= 1;
  }

#pragma unroll
  for (int j = 0; j < 4; ++j) {
    float sa = lrowA[j], sb = lrowB[j];
    sa += __shfl_xor(sa, 1); sb += __shfl_xor(sb, 1);
    sa += __shfl_xor(sa, 2); sb += __shfl_xor(sb, 2);
    sa += __shfl_xor(sa, 4); sb += __shfl_xor(sb, 4);
    sa += __shfl_xor(sa, 8); sb += __shfl_xor(sb, 8);
    lrowA[j] = sa; lrowB[j] = sb;
  }

#pragma unroll
  for (int dt = 0; dt < 4; ++dt)
#pragma unroll
    for (int j = 0; j < 4; ++j) {
      const int d = h * 64 + dt * 16 + lo;
      const int na = b * SEQ + q0 + hi * 4 + j;
      ctx[(size_t)na * 512 + d] = __float2bfloat16(oaccA[dt][j] / lrowA[j]);
      const int nb = na + 64;
      ctx[(size_t)nb * 512 + d] = __float2bfloat16(oaccB[dt][j] / lrowB[j]);
    }
}

// ---------------- GLU, 8 channels/thread ----------------
__global__ __launch_bounds__(256) void glu8_kernel(const __hip_bfloat16* __restrict__ y,
                                                   __hip_bfloat16* __restrict__ o) {
  const int i = blockIdx.x * 256 + threadIdx.x;
  const int c8 = i & 63;
  const int n = i >> 6;
  const short* yp = reinterpret_cast<const short*>(y) + (size_t)n * 1024 + c8 * 8;
  bf16x8 a = *reinterpret_cast<const bf16x8*>(yp);
  bf16x8 g = *reinterpret_cast<const bf16x8*>(yp + 512);
  bf16x8 ov;
#pragma unroll
  for (int j = 0; j < 8; ++j) {
    const float av = bfs2f(a[j]);
    const float gv = bfs2f(g[j]);
    ov[j] = f2bfs(av / (1.f + __expf(-gv)));
  }
  *reinterpret_cast<bf16x8*>(reinterpret_cast<short*>(o) + (size_t)n * 512 + c8 * 8) = ov;
}

// ---------------- depthwise conv K=31 + BN + SiLU, bf16 in, 8 ch/thread ----------
__global__ __launch_bounds__(256) void dwconv8_kernel(const __hip_bfloat16* __restrict__ cin,
                                                      const __hip_bfloat16* __restrict__ wkT,
                                                      const __hip_bfloat16* __restrict__ cb,
                                                      const __hip_bfloat16* __restrict__ bng,
                                                      const __hip_bfloat16* __restrict__ bnb,
                                                      const __hip_bfloat16* __restrict__ bnm,
                                                      const __hip_bfloat16* __restrict__ bnv,
                                                      __hip_bfloat16* __restrict__ outp) {
  const int i = blockIdx.x * 256 + threadIdx.x;
  const int c8 = i & 63;
  const int n = i >> 6;
  const int t = n & 1023;
  const int base = n - t;
  const int co = c8 * 8;

  float acc[8];
  {
    bf16x8 bv = *reinterpret_cast<const bf16x8*>(cb + co);
#pragma unroll
    for (int j = 0; j < 8; ++j) acc[j] = bfs2f(bv[j]);
  }
  const int k0 = (t >= 15) ? 0 : (15 - t);
  const int k1 = (t <= SEQ - 16) ? 31 : (SEQ - 1 - t + 16);
  const short* cin_s = reinterpret_cast<const short*>(cin);
  const short* wk_s = reinterpret_cast<const short*>(wkT);
  for (int k = k0; k < k1; ++k) {
    const int ts = t + k - 15;
    bf16x8 xv = *reinterpret_cast<const bf16x8*>(cin_s + (((size_t)(base + ts)) << 9) + co);
    bf16x8 wv = *reinterpret_cast<const bf16x8*>(wk_s + k * 512 + co);
#pragma unroll
    for (int j = 0; j < 8; ++j) acc[j] += bfs2f(xv[j]) * bfs2f(wv[j]);
  }
  bf16x8 g = *reinterpret_cast<const bf16x8*>(bng + co);
  bf16x8 bb = *reinterpret_cast<const bf16x8*>(bnb + co);
  bf16x8 bm = *reinterpret_cast<const bf16x8*>(bnm + co);
  bf16x8 bvv = *reinterpret_cast<const bf16x8*>(bnv + co);
  bf16x8 ov;
#pragma unroll
  for (int j = 0; j < 8; ++j) {
    const float scl = bfs2f(g[j]) * rsqrtf(bfs2f(bvv[j]) + 1e-5f);
    float v = (acc[j] - bfs2f(bm[j])) * scl + bfs2f(bb[j]);
    v = v / (1.f + __expf(-v));
    ov[j] = f2bfs(v);
  }
  *reinterpret_cast<bf16x8*>(reinterpret_cast<short*>(outp) + ((size_t)n << 9) + co) = ov;
}

extern "C" void kernel_launch(void* const* d_in, const int* in_sizes, int n_in,
                              void* d_out, int out_size, void* d_ws, size_t ws_size,
                              hipStream_t stream) {
  float* out = (float*)d_out;  // confirmed: f32 in / f32 out
  if (ws_size < ((size_t)80 << 20)) {
    ws_bad_kernel<<<1, 64, 0, stream>>>(out);  // sentinel 5000
    return;
  }

  const float* x = (const float*)d_in[0];

  char* ws = (char*)d_ws;
  float*          xs = (float*)ws;                                       // 0-16 MB
  __hip_bfloat16* t0 = (__hip_bfloat16*)(ws + ((size_t)16 << 20));       // 16-24 MB
  __hip_bfloat16* t1 = (__hip_bfloat16*)(ws + ((size_t)24 << 20));       // 24-48 MB
  __hip_bfloat16* t2 = (__hip_bfloat16*)(ws + ((size_t)56 << 20));       // 56-64 MB
  __hip_bfloat16* wc = (__hip_bfloat16*)(ws + ((size_t)64 << 20));       // 64-76 MB
  __hip_bfloat16* vT = t1 + (size_t)NTOK * 1536;                         // 48-56 MB

  __hip_bfloat16* wc_ff1_w1 = wc + 0;
  __hip_bfloat16* wc_ff1_w2 = wc + 1048576;
  __hip_bfloat16* wc_qkv_w  = wc + 2097152;
  __hip_bfloat16* wc_out_w  = wc + 2883584;
  __hip_bfloat16* wc_pw1_w  = wc + 3145728;
  __hip_bfloat16* wc_pw2_w  = wc + 3670016;
  __hip_bfloat16* wc_ff2_w1 = wc + 3932160;
  __hip_bfloat16* wc_ff2_w2 = wc + 4980736;
  __hip_bfloat16* wc_dwT    = wc + 6029312;      // [31][512] bf16 transposed
  __hip_bfloat16* sm        = wc + 6045184;
  __hip_bfloat16* c_ln1_g = sm + 0,     *c_ln1_b = sm + 512,   *c_ff1_b1 = sm + 1024;
  __hip_bfloat16* c_ff1_b2 = sm + 3072, *c_lna_g = sm + 3584,  *c_lna_b = sm + 4096;
  __hip_bfloat16* c_qkv_b = sm + 4608,  *c_out_b = sm + 6144,  *c_lnc_g = sm + 6656;
  __hip_bfloat16* c_lnc_b = sm + 7168,  *c_pw1_b = sm + 7680,  *c_dw_b = sm + 8704;
  __hip_bfloat16* c_bn_g = sm + 9216,   *c_bn_b = sm + 9728,   *c_bn_m = sm + 10240;
  __hip_bfloat16* c_bn_v = sm + 10752,  *c_pw2_b = sm + 11264, *c_ln2_g = sm + 11776;
  __hip_bfloat16* c_ln2_b = sm + 12288, *c_ff2_b1 = sm + 12800, *c_ff2_b2 = sm + 14848;
  __hip_bfloat16* c_lnf_g = sm + 15360, *c_lnf_b = sm + 15872;

  // --- input normalization (f32 world) ---
  {
    WPack wp;
    wp.s[0] = {(const float*)d_in[3],  0,      131072};  // ff1_w1
    wp.s[1] = {(const float*)d_in[5],  131072, 131072};  // ff1_w2
    wp.s[2] = {(const float*)d_in[9],  262144, 98304};   // qkv_w
    wp.s[3] = {(const float*)d_in[11], 360448, 32768};   // out_w
    wp.s[4] = {(const float*)d_in[15], 393216, 65536};   // pw1_w
    wp.s[5] = {(const float*)d_in[23], 458752, 32768};   // pw2_w
    wp.s[6] = {(const float*)d_in[27], 491520, 131072};  // ff2_w1
    wp.s[7] = {(const float*)d_in[29], 622592, 131072};  // ff2_w2
    cast_wall_kernel<<<2944, 256, 0, stream>>>(wp, wc);
  }
  cast_dww_kernel<<<1, 256, 0, stream>>>((const float*)d_in[17], wc_dwT);
  PtrPack pk;
  const int small_idx[23] = {1, 2, 4, 6, 7, 8, 10, 12, 13, 14, 16, 18,
                             19, 20, 21, 22, 24, 25, 26, 28, 30, 31, 32};
  for (int t = 0; t < 23; ++t) pk.p[t] = d_in[small_idx[t]];
  cast_small_kernel<<<1, 256, 0, stream>>>(pk, sm);

  // --- FF1 (half-scale): xs = 1.5*x + 0.5*(silu(ln(x)@w1)@w2 + b2) ---
  ln_kernel<<<2048, 256, 0, stream>>>(x, c_ln1_g, c_ln1_b, t0);
  gemm8p_silu<<<dim3(32, 8), 512, 0, stream>>>(t0, wc_ff1_w1, c_ff1_b1, t1, 512, 2048);
  gemm64_resid<<<dim3(128, 4), 256, 0, stream>>>(t1, wc_ff1_w2, c_ff1_b2, x, xs, 2048, 1.5f, 0.5f);

  // --- Attention (qkv GEMM with fused V-transpose; MFMA flash v6) ---
  ln_kernel<<<2048, 256, 0, stream>>>(xs, c_lna_g, c_lna_b, t0);
  gemm_bt<3><<<dim3(64, 12), 256, 0, stream>>>(t0, wc_qkv_w, c_qkv_b, t1, nullptr, vT, 512, 1536, 0.f, 0.f);
  attn_kernel<<<512, 256, 0, stream>>>(t1, vT, t2);
  gemm64_resid<<<dim3(128, 4), 256, 0, stream>>>(t2, wc_out_w, c_out_b, xs, xs, 512, 1.0f, 1.0f);

  // --- Conv module ---
  ln_kernel<<<2048, 256, 0, stream>>>(xs, c_lnc_g, c_lnc_b, t0);
  gemm_bt<0><<<dim3(64, 8), 256, 0, stream>>>(t0, wc_pw1_w, c_pw1_b, t1, nullptr, nullptr, 512, 1024, 0.f, 0.f);
  glu8_kernel<<<2048, 256, 0, stream>>>(t1, t2);
  dwconv8_kernel<<<2048, 256, 0, stream>>>(t2, wc_dwT, c_dw_b, c_bn_g, c_bn_b, c_bn_m, c_bn_v, t0);
  gemm64_resid<<<dim3(128, 4), 256, 0, stream>>>(t0, wc_pw2_w, c_pw2_b, xs, xs, 512, 2.0f, 1.0f);

  // --- FF2 (half-scale) ---
  ln_kernel<<<2048, 256, 0, stream>>>(xs, c_ln2_g, c_ln2_b, t0);
  gemm8p_silu<<<dim3(32, 8), 512, 0, stream>>>(t0, wc_ff2_w1, c_ff2_b1, t1, 512, 2048);
  gemm64_resid<<<dim3(128, 4), 256, 0, stream>>>(t1, wc_ff2_w2, c_ff2_b2, xs, xs, 2048, 1.5f, 0.5f);

  // --- Final LN -> FP32 out ---
  lnf_kernel<<<2048, 256, 0, stream>>>(xs, c_lnf_g, c_lnf_b, out);
}

// Round 18
// 302.123 us; speedup vs baseline: 1.0270x; 1.0270x over previous
//
#include <hip/hip_runtime.h>
#include <hip/hip_bf16.h>

typedef __attribute__((ext_vector_type(8))) short bf16x8;
typedef __attribute__((ext_vector_type(4))) short bf16x4;
typedef __attribute__((ext_vector_type(4))) float f32x4;

#define NTOK 8192
#define SEQ  1024
#define NH   8

__device__ __forceinline__ float bfs2f(short s) {
  union { unsigned u; float f; } x; x.u = ((unsigned)(unsigned short)s) << 16; return x.f;
}
__device__ __forceinline__ short f2bfs(float f) {
  __hip_bfloat16 h = __float2bfloat16(f);
  return *reinterpret_cast<short*>(&h);
}
__device__ __forceinline__ float bfp2f(const __hip_bfloat16* p) {
  return bfs2f(*reinterpret_cast<const short*>(p));
}

__device__ __forceinline__ void gld16(const void* g, void* l) {
  __builtin_amdgcn_global_load_lds(
      (__attribute__((address_space(1))) void*)const_cast<void*>(g),
      (__attribute__((address_space(3))) void*)l, 16, 0, 0);
}

// ---------------- fused f32 weight -> bf16 cast (all big tensors, 1 launch) ------
struct WSeg { const float* src; unsigned dst_off; unsigned nvec; };
struct WPack { WSeg s[8]; };

__global__ __launch_bounds__(256) void cast_wall_kernel(WPack p,
                                                        __hip_bfloat16* __restrict__ dst) {
  unsigned v = blockIdx.x * 256 + threadIdx.x;
#pragma unroll
  for (int t = 0; t < 8; ++t) {
    if (v < p.s[t].nvec) {
      const float* s = p.s[t].src + (size_t)v * 8;
      f32x4 a = *reinterpret_cast<const f32x4*>(s);
      f32x4 b = *reinterpret_cast<const f32x4*>(s + 4);
      bf16x8 o;
#pragma unroll
      for (int j = 0; j < 4; ++j) { o[j] = f2bfs(a[j]); o[4 + j] = f2bfs(b[j]); }
      *reinterpret_cast<bf16x8*>(reinterpret_cast<short*>(dst) +
                                 (size_t)(p.s[t].dst_off + v) * 8) = o;
      return;
    }
    v -= p.s[t].nvec;
  }
}

// ---------------- dw_w f32 [512][31] -> bf16 transposed [31][512] ----------------
__global__ __launch_bounds__(256) void cast_dww_kernel(const float* __restrict__ src,
                                                       __hip_bfloat16* __restrict__ dst) {
  for (int k = 0; k < 31; ++k)
    for (int c = threadIdx.x; c < 512; c += 256)
      dst[k * 512 + c] = __float2bfloat16(src[c * 31 + k]);
}

struct PtrPack { const void* p[23]; };

__global__ __launch_bounds__(256) void cast_small_kernel(PtrPack pk,
                                                         __hip_bfloat16* __restrict__ dst) {
  constexpr int sizes[23] = {512, 512, 2048, 512, 512, 512, 1536, 512, 512, 512, 1024, 512,
                             512, 512, 512, 512, 512, 512, 512, 2048, 512, 512, 512};
  int off = 0;
  for (int t = 0; t < 23; ++t) {
    const int n = sizes[t];
    for (int i = threadIdx.x; i < n; i += 256)
      dst[off + i] = __float2bfloat16(((const float*)pk.p[t])[i]);
    off += n;
  }
}

__global__ void ws_bad_kernel(float* __restrict__ out) {
  if (threadIdx.x == 0) out[0] = 5000.f;
}

// ---------------- LayerNorm: fp32 in -> bf16 out (D=512) ----------------
__global__ __launch_bounds__(256) void ln_kernel(const float* __restrict__ in,
                                                 const __hip_bfloat16* __restrict__ g,
                                                 const __hip_bfloat16* __restrict__ b,
                                                 __hip_bfloat16* __restrict__ out) {
  const int wv = threadIdx.x >> 6, ln = threadIdx.x & 63;
  const int row = blockIdx.x * 4 + wv;
  const float* p = in + (size_t)row * 512 + ln * 8;
  float v[8];
  {
    const f32x4* p4 = reinterpret_cast<const f32x4*>(p);
    f32x4 a = p4[0], c = p4[1];
#pragma unroll
    for (int j = 0; j < 4; ++j) { v[j] = a[j]; v[4 + j] = c[j]; }
  }
  float s = 0.f;
#pragma unroll
  for (int j = 0; j < 8; ++j) s += v[j];
  for (int m = 1; m < 64; m <<= 1) s += __shfl_xor(s, m);
  const float mean = s * (1.f / 512.f);
  float q = 0.f;
#pragma unroll
  for (int j = 0; j < 8; ++j) { float d = v[j] - mean; q += d * d; }
  for (int m = 1; m < 64; m <<= 1) q += __shfl_xor(q, m);
  const float rstd = rsqrtf(q * (1.f / 512.f) + 1e-5f);
  bf16x8 gg = *reinterpret_cast<const bf16x8*>(g + ln * 8);
  bf16x8 bb = *reinterpret_cast<const bf16x8*>(b + ln * 8);
  bf16x8 ov;
#pragma unroll
  for (int j = 0; j < 8; ++j)
    ov[j] = f2bfs((v[j] - mean) * rstd * bfs2f(gg[j]) + bfs2f(bb[j]));
  *reinterpret_cast<bf16x8*>(out + (size_t)row * 512 + ln * 8) = ov;
}

// ---------------- final LayerNorm: fp32 in -> FP32 out ----------------
__global__ __launch_bounds__(256) void lnf_kernel(const float* __restrict__ in,
                                                  const __hip_bfloat16* __restrict__ g,
                                                  const __hip_bfloat16* __restrict__ b,
                                                  float* __restrict__ out) {
  const int wv = threadIdx.x >> 6, ln = threadIdx.x & 63;
  const int row = blockIdx.x * 4 + wv;
  const float* p = in + (size_t)row * 512 + ln * 8;
  float v[8];
  {
    const f32x4* p4 = reinterpret_cast<const f32x4*>(p);
    f32x4 a = p4[0], c = p4[1];
#pragma unroll
    for (int j = 0; j < 4; ++j) { v[j] = a[j]; v[4 + j] = c[j]; }
  }
  float s = 0.f;
#pragma unroll
  for (int j = 0; j < 8; ++j) s += v[j];
  for (int m = 1; m < 64; m <<= 1) s += __shfl_xor(s, m);
  const float mean = s * (1.f / 512.f);
  float q = 0.f;
#pragma unroll
  for (int j = 0; j < 8; ++j) { float d = v[j] - mean; q += d * d; }
  for (int m = 1; m < 64; m <<= 1) q += __shfl_xor(q, m);
  const float rstd = rsqrtf(q * (1.f / 512.f) + 1e-5f);
  bf16x8 gg = *reinterpret_cast<const bf16x8*>(g + ln * 8);
  bf16x8 bb = *reinterpret_cast<const bf16x8*>(b + ln * 8);
  f32x4 o0, o1;
#pragma unroll
  for (int j = 0; j < 4; ++j) {
    o0[j] = (v[j] - mean) * rstd * bfs2f(gg[j]) + bfs2f(bb[j]);
    o1[j] = (v[4 + j] - mean) * rstd * bfs2f(gg[4 + j]) + bfs2f(bb[4 + j]);
  }
  float* op = out + (size_t)row * 512 + ln * 8;
  *reinterpret_cast<f32x4*>(op) = o0;
  *reinterpret_cast<f32x4*>(op + 4) = o1;
}

// ---------------- MFMA GEMM (m97 + T2 swizzle, XCD-swizzled, 3 blocks/CU) --------
// EPI 0: bf16 out ; EPI 1: bf16 silu ; EPI 2: fp32 resid update ;
// EPI 3: qkv — Q/K to outb, V written TRANSPOSED to vTout[b,h,d,s] (short4).
template <int EPI>
__global__ __launch_bounds__(256, 3) void gemm_bt(const __hip_bfloat16* __restrict__ A,
                                                  const __hip_bfloat16* __restrict__ W,
                                                  const __hip_bfloat16* __restrict__ bias,
                                                  __hip_bfloat16* __restrict__ outb,
                                                  float* __restrict__ resid,
                                                  __hip_bfloat16* __restrict__ vTout,
                                                  int K, int M, float alpha, float beta) {
  __shared__ __align__(16) __hip_bfloat16 As[128 * 64];
  __shared__ __align__(16) __hip_bfloat16 Bs[128 * 64];
  const int tid = threadIdx.x;
  const int wv = tid >> 6, ln = tid & 63;
  const int hi = ln >> 4, lo = ln & 15;
  const int lo7 = lo & 7;
  const int gx = gridDim.x;
  const int nwg = gx * gridDim.y;
  const int t = blockIdx.y * gx + blockIdx.x;
  const int w = (t & 7) * (nwg >> 3) + (t >> 3);
  const int n0 = (w & (gx - 1)) * 128;
  const int m0 = (w / gx) * 128;
  const int wr = wv >> 1, wc = wv & 1;
  const int srow = ln >> 3;
  const int scolz = (((ln & 7) ^ srow) << 3);   // swizzled source granule

  f32x4 acc[4][4] = {};

  for (int k0 = 0; k0 < K; k0 += 64) {
    __syncthreads();
#pragma unroll
    for (int i = 0; i < 4; ++i) {
      const int grp = i * 4 + wv;
      const int row = grp * 8 + srow;
      gld16(A + (size_t)(n0 + row) * K + k0 + scolz, As + grp * 512);
      gld16(W + (size_t)(m0 + row) * K + k0 + scolz, Bs + grp * 512);
    }
    __syncthreads();
#pragma unroll
    for (int kk2 = 0; kk2 < 2; ++kk2) {
      const int g0 = ((kk2 * 4 + hi) ^ lo7) << 3;   // swizzled read granule
      bf16x8 af[4], bfr[4];
#pragma unroll
      for (int r = 0; r < 4; ++r)
        af[r] = *reinterpret_cast<const bf16x8*>(As + (wr * 64 + r * 16 + lo) * 64 + g0);
#pragma unroll
      for (int c = 0; c < 4; ++c)
        bfr[c] = *reinterpret_cast<const bf16x8*>(Bs + (wc * 64 + c * 16 + lo) * 64 + g0);
#pragma unroll
      for (int r = 0; r < 4; ++r)
#pragma unroll
        for (int c = 0; c < 4; ++c)
          acc[r][c] = __builtin_amdgcn_mfma_f32_16x16x32_bf16(af[r], bfr[c], acc[r][c], 0, 0, 0);
    }
  }

#pragma unroll
  for (int r = 0; r < 4; ++r) {
#pragma unroll
    for (int c = 0; c < 4; ++c) {
      const int m = m0 + wc * 64 + c * 16 + lo;
      const float bv = bfp2f(bias + m);
      const int nb = n0 + wr * 64 + r * 16 + hi * 4;
      if constexpr (EPI == 3) {
        if (m >= 1024) {  // V part -> transposed store
          const int hd = m - 1024;
          __hip_bfloat16* vp = vTout +
              ((size_t)((nb >> 10) * NH + (hd >> 6)) * 64 + (hd & 63)) * 1024 + (nb & 1023);
          bf16x4 vv;
#pragma unroll
          for (int j = 0; j < 4; ++j) vv[j] = f2bfs(acc[r][c][j] + bv);
          *reinterpret_cast<bf16x4*>(vp) = vv;
          continue;
        }
      }
#pragma unroll
      for (int j = 0; j < 4; ++j) {
        const int n = nb + j;
        float v = acc[r][c][j] + bv;
        if constexpr (EPI == 1) v = v / (1.f + __expf(-v));
        if constexpr (EPI == 2) {
          const size_t idx = (size_t)n * 512 + m;
          resid[idx] = alpha * resid[idx] + beta * v;
        } else {
          outb[(size_t)n * M + m] = __float2bfloat16(v);
        }
      }
    }
  }
}

// ---------------- MFMA GEMM, M=512 resid: BM=64 x BN=128 + T2 swizzle ------------
__global__ __launch_bounds__(256, 4) void gemm64_resid(const __hip_bfloat16* __restrict__ A,
                                                       const __hip_bfloat16* __restrict__ W,
                                                       const __hip_bfloat16* __restrict__ bias,
                                                       const float* __restrict__ rsrc,
                                                       float* __restrict__ resid,
                                                       int K, float alpha, float beta) {
  __shared__ __align__(16) __hip_bfloat16 As[64 * 64];
  __shared__ __align__(16) __hip_bfloat16 Bs[128 * 64];
  const int tid = threadIdx.x;
  const int wv = tid >> 6, ln = tid & 63;
  const int hi = ln >> 4, lo = ln & 15;
  const int lo7 = lo & 7;
  const int gx = gridDim.x;
  const int nwg = gx * gridDim.y;
  const int t = blockIdx.y * gx + blockIdx.x;
  const int w = (t & 7) * (nwg >> 3) + (t >> 3);
  const int n0 = (w & (gx - 1)) * 64;
  const int m0 = (w / gx) * 128;
  const int wr = wv >> 1, wc = wv & 1;
  const int srow = ln >> 3;
  const int scolz = (((ln & 7) ^ srow) << 3);

  f32x4 acc[2][4] = {};

  for (int k0 = 0; k0 < K; k0 += 64) {
    __syncthreads();
#pragma unroll
    for (int i = 0; i < 2; ++i) {
      const int grp = i * 4 + wv;
      gld16(A + (size_t)(n0 + grp * 8 + srow) * K + k0 + scolz, As + grp * 512);
    }
#pragma unroll
    for (int i = 0; i < 4; ++i) {
      const int grp = i * 4 + wv;
      gld16(W + (size_t)(m0 + grp * 8 + srow) * K + k0 + scolz, Bs + grp * 512);
    }
    __syncthreads();
#pragma unroll
    for (int kk2 = 0; kk2 < 2; ++kk2) {
      const int g0 = ((kk2 * 4 + hi) ^ lo7) << 3;
      bf16x8 af[2], bfr[4];
#pragma unroll
      for (int r = 0; r < 2; ++r)
        af[r] = *reinterpret_cast<const bf16x8*>(As + (wr * 32 + r * 16 + lo) * 64 + g0);
#pragma unroll
      for (int c = 0; c < 4; ++c)
        bfr[c] = *reinterpret_cast<const bf16x8*>(Bs + (wc * 64 + c * 16 + lo) * 64 + g0);
#pragma unroll
      for (int r = 0; r < 2; ++r)
#pragma unroll
        for (int c = 0; c < 4; ++c)
          acc[r][c] = __builtin_amdgcn_mfma_f32_16x16x32_bf16(af[r], bfr[c], acc[r][c], 0, 0, 0);
    }
  }

#pragma unroll
  for (int r = 0; r < 2; ++r) {
#pragma unroll
    for (int c = 0; c < 4; ++c) {
      const int m = m0 + wc * 64 + c * 16 + lo;
      const float bv = bfp2f(bias + m);
#pragma unroll
      for (int j = 0; j < 4; ++j) {
        const int n = n0 + wr * 32 + r * 16 + hi * 4 + j;
        const size_t idx = (size_t)n * 512 + m;
        resid[idx] = alpha * rsrc[idx] + beta * (acc[r][c][j] + bv);
      }
    }
  }
}

// ---------------- MFMA flash attention v6: 2 q-tiles/wave, K/V frag reuse --------
__global__ __launch_bounds__(256, 2) void attn_kernel(const __hip_bfloat16* __restrict__ qkv,
                                                      const __hip_bfloat16* __restrict__ vT,
                                                      __hip_bfloat16* __restrict__ ctx) {
  __shared__ __align__(16) short Ks[2][64 * 64];
  __shared__ __align__(16) short Vs[2][64 * 64];
  __shared__ __align__(16) short P[4][16][64];
  const int tid = threadIdx.x;
  const int wv = tid >> 6, ln = tid & 63;
  const int hi = ln >> 4, lo = ln & 15;
  const int lo7 = lo & 7;
  const int blk = ((blockIdx.x & 7) << 6) | (blockIdx.x >> 3);
  const int qt = blk & 7, h = (blk >> 3) & 7, b = blk >> 6;
  const int q0 = qt * 128 + wv * 16;   // tile A rows; tile B = q0 + 64

  const int srow8 = ln >> 3;
  const int gsrc = (ln & 7) ^ srow8;

  bf16x8 aq0a, aq1a, aq0b, aq1b;
  {
    const __hip_bfloat16* qpa = qkv + (size_t)(b * SEQ + q0 + lo) * 1536 + h * 64 + hi * 8;
    const __hip_bfloat16* qpb = qpa + (size_t)64 * 1536;
    bf16x8 r0 = *reinterpret_cast<const bf16x8*>(qpa);
    bf16x8 r1 = *reinterpret_cast<const bf16x8*>(qpa + 32);
    bf16x8 r2 = *reinterpret_cast<const bf16x8*>(qpb);
    bf16x8 r3 = *reinterpret_cast<const bf16x8*>(qpb + 32);
#pragma unroll
    for (int j = 0; j < 8; ++j) {
      aq0a[j] = f2bfs(bfs2f(r0[j]) * 0.125f);
      aq1a[j] = f2bfs(bfs2f(r1[j]) * 0.125f);
      aq0b[j] = f2bfs(bfs2f(r2[j]) * 0.125f);
      aq1b[j] = f2bfs(bfs2f(r3[j]) * 0.125f);
    }
  }

  const __hip_bfloat16* kbase = qkv + 512 + h * 64 + (size_t)b * SEQ * 1536;
  const __hip_bfloat16* vbase = vT + (size_t)(b * NH + h) * 64 * 1024;

  f32x4 oaccA[4] = {}, oaccB[4] = {};
  float lrowA[4] = {0.f, 0.f, 0.f, 0.f};
  float lrowB[4] = {0.f, 0.f, 0.f, 0.f};

#pragma unroll
  for (int c = 0; c < 2; ++c) {
    const int r = c * 32 + wv * 8 + srow8;
    gld16(kbase + (size_t)r * 1536 + gsrc * 8, &Ks[0][(c * 32 + wv * 8) * 64]);
    gld16(vbase + (size_t)r * 1024 + gsrc * 8, &Vs[0][(c * 32 + wv * 8) * 64]);
  }
  __syncthreads();

  int cb = 0;
  for (int kt = 0; kt < 16; ++kt) {
    if (kt < 15) {
      const int kb2 = (kt + 1) * 64;
#pragma unroll
      for (int c = 0; c < 2; ++c) {
        const int r = c * 32 + wv * 8 + srow8;
        gld16(kbase + (size_t)(kb2 + r) * 1536 + gsrc * 8,
              &Ks[cb ^ 1][(c * 32 + wv * 8) * 64]);
        gld16(vbase + (size_t)r * 1024 + kb2 + gsrc * 8,
              &Vs[cb ^ 1][(c * 32 + wv * 8) * 64]);
      }
    }

    bf16x8 bk0[4], bk1[4];
#pragma unroll
    for (int nt = 0; nt < 4; ++nt) {
      const short* kr = &Ks[cb][(nt * 16 + lo) * 64];
      bk0[nt] = *reinterpret_cast<const bf16x8*>(kr + ((hi ^ lo7) << 3));
      bk1[nt] = *reinterpret_cast<const bf16x8*>(kr + (((hi + 4) ^ lo7) << 3));
    }
    f32x4 scA[4] = {}, scB[4] = {};
#pragma unroll
    for (int nt = 0; nt < 4; ++nt) {
      scA[nt] = __builtin_amdgcn_mfma_f32_16x16x32_bf16(aq0a, bk0[nt], scA[nt], 0, 0, 0);
      scA[nt] = __builtin_amdgcn_mfma_f32_16x16x32_bf16(aq1a, bk1[nt], scA[nt], 0, 0, 0);
      scB[nt] = __builtin_amdgcn_mfma_f32_16x16x32_bf16(aq0b, bk0[nt], scB[nt], 0, 0, 0);
      scB[nt] = __builtin_amdgcn_mfma_f32_16x16x32_bf16(aq1b, bk1[nt], scB[nt], 0, 0, 0);
    }

    bf16x8 bv0[4], bv1[4];
#pragma unroll
    for (int dt = 0; dt < 4; ++dt) {
      const short* vr = &Vs[cb][(dt * 16 + lo) * 64];
      bv0[dt] = *reinterpret_cast<const bf16x8*>(vr + ((hi ^ lo7) << 3));
      bv1[dt] = *reinterpret_cast<const bf16x8*>(vr + (((hi + 4) ^ lo7) << 3));
    }

#pragma unroll
    for (int j = 0; j < 4; ++j) {
      const int prow = hi * 4 + j;
      const int pswz = (prow & 7) << 3;
#pragma unroll
      for (int nt = 0; nt < 4; ++nt) {
        const float p = __expf(scA[nt][j]);
        P[wv][prow][(nt * 16 + lo) ^ pswz] = f2bfs(p);
        lrowA[j] += p;
      }
    }
    asm volatile("" ::: "memory");
    {
      const short* pr = &P[wv][lo][0];
      bf16x8 ap0 = *reinterpret_cast<const bf16x8*>(pr + ((hi ^ lo7) << 3));
      bf16x8 ap1 = *reinterpret_cast<const bf16x8*>(pr + (((hi + 4) ^ lo7) << 3));
#pragma unroll
      for (int dt = 0; dt < 4; ++dt) {
        oaccA[dt] = __builtin_amdgcn_mfma_f32_16x16x32_bf16(ap0, bv0[dt], oaccA[dt], 0, 0, 0);
        oaccA[dt] = __builtin_amdgcn_mfma_f32_16x16x32_bf16(ap1, bv1[dt], oaccA[dt], 0, 0, 0);
      }
    }
    asm volatile("" ::: "memory");

#pragma unroll
    for (int j = 0; j < 4; ++j) {
      const int prow = hi * 4 + j;
      const int pswz = (prow & 7) << 3;
#pragma unroll
      for (int nt = 0; nt < 4; ++nt) {
        const float p = __expf(scB[nt][j]);
        P[wv][prow][(nt * 16 + lo) ^ pswz] = f2bfs(p);
        lrowB[j] += p;
      }
    }
    asm volatile("" ::: "memory");
    {
      const short* pr = &P[wv][lo][0];
      bf16x8 ap0 = *reinterpret_cast<const bf16x8*>(pr + ((hi ^ lo7) << 3));
      bf16x8 ap1 = *reinterpret_cast<const bf16x8*>(pr + (((hi + 4) ^ lo7) << 3));
#pragma unroll
      for (int dt = 0; dt < 4; ++dt) {
        oaccB[dt] = __builtin_amdgcn_mfma_f32_16x16x32_bf16(ap0, bv0[dt], oaccB[dt], 0, 0, 0);
        oaccB[dt] = __builtin_amdgcn_mfma_f32_16x16x32_bf16(ap1, bv1[dt], oaccB[dt], 0, 0, 0);
      }
    }
    __syncthreads();
    cb ^= 1;
  }

#pragma unroll
  for (int j = 0; j < 4; ++j) {
    float sa = lrowA[j], sb = lrowB[j];
    sa += __shfl_xor(sa, 1); sb += __shfl_xor(sb, 1);
    sa += __shfl_xor(sa, 2); sb += __shfl_xor(sb, 2);
    sa += __shfl_xor(sa, 4); sb += __shfl_xor(sb, 4);
    sa += __shfl_xor(sa, 8); sb += __shfl_xor(sb, 8);
    lrowA[j] = sa; lrowB[j] = sb;
  }

#pragma unroll
  for (int dt = 0; dt < 4; ++dt)
#pragma unroll
    for (int j = 0; j < 4; ++j) {
      const int d = h * 64 + dt * 16 + lo;
      const int na = b * SEQ + q0 + hi * 4 + j;
      ctx[(size_t)na * 512 + d] = __float2bfloat16(oaccA[dt][j] / lrowA[j]);
      const int nb = na + 64;
      ctx[(size_t)nb * 512 + d] = __float2bfloat16(oaccB[dt][j] / lrowB[j]);
    }
}

// ---------------- GLU, 8 channels/thread ----------------
__global__ __launch_bounds__(256) void glu8_kernel(const __hip_bfloat16* __restrict__ y,
                                                   __hip_bfloat16* __restrict__ o) {
  const int i = blockIdx.x * 256 + threadIdx.x;
  const int c8 = i & 63;
  const int n = i >> 6;
  const short* yp = reinterpret_cast<const short*>(y) + (size_t)n * 1024 + c8 * 8;
  bf16x8 a = *reinterpret_cast<const bf16x8*>(yp);
  bf16x8 g = *reinterpret_cast<const bf16x8*>(yp + 512);
  bf16x8 ov;
#pragma unroll
  for (int j = 0; j < 8; ++j) {
    const float av = bfs2f(a[j]);
    const float gv = bfs2f(g[j]);
    ov[j] = f2bfs(av / (1.f + __expf(-gv)));
  }
  *reinterpret_cast<bf16x8*>(reinterpret_cast<short*>(o) + (size_t)n * 512 + c8 * 8) = ov;
}

// ---------------- depthwise conv K=31 + BN + SiLU, bf16 in, 8 ch/thread ----------
__global__ __launch_bounds__(256) void dwconv8_kernel(const __hip_bfloat16* __restrict__ cin,
                                                      const __hip_bfloat16* __restrict__ wkT,
                                                      const __hip_bfloat16* __restrict__ cb,
                                                      const __hip_bfloat16* __restrict__ bng,
                                                      const __hip_bfloat16* __restrict__ bnb,
                                                      const __hip_bfloat16* __restrict__ bnm,
                                                      const __hip_bfloat16* __restrict__ bnv,
                                                      __hip_bfloat16* __restrict__ outp) {
  const int i = blockIdx.x * 256 + threadIdx.x;
  const int c8 = i & 63;
  const int n = i >> 6;
  const int t = n & 1023;
  const int base = n - t;
  const int co = c8 * 8;

  float acc[8];
  {
    bf16x8 bv = *reinterpret_cast<const bf16x8*>(cb + co);
#pragma unroll
    for (int j = 0; j < 8; ++j) acc[j] = bfs2f(bv[j]);
  }
  const int k0 = (t >= 15) ? 0 : (15 - t);
  const int k1 = (t <= SEQ - 16) ? 31 : (SEQ - 1 - t + 16);
  const short* cin_s = reinterpret_cast<const short*>(cin);
  const short* wk_s = reinterpret_cast<const short*>(wkT);
  for (int k = k0; k < k1; ++k) {
    const int ts = t + k - 15;
    bf16x8 xv = *reinterpret_cast<const bf16x8*>(cin_s + (((size_t)(base + ts)) << 9) + co);
    bf16x8 wv = *reinterpret_cast<const bf16x8*>(wk_s + k * 512 + co);
#pragma unroll
    for (int j = 0; j < 8; ++j) acc[j] += bfs2f(xv[j]) * bfs2f(wv[j]);
  }
  bf16x8 g = *reinterpret_cast<const bf16x8*>(bng + co);
  bf16x8 bb = *reinterpret_cast<const bf16x8*>(bnb + co);
  bf16x8 bm = *reinterpret_cast<const bf16x8*>(bnm + co);
  bf16x8 bvv = *reinterpret_cast<const bf16x8*>(bnv + co);
  bf16x8 ov;
#pragma unroll
  for (int j = 0; j < 8; ++j) {
    const float scl = bfs2f(g[j]) * rsqrtf(bfs2f(bvv[j]) + 1e-5f);
    float v = (acc[j] - bfs2f(bm[j])) * scl + bfs2f(bb[j]);
    v = v / (1.f + __expf(-v));
    ov[j] = f2bfs(v);
  }
  *reinterpret_cast<bf16x8*>(reinterpret_cast<short*>(outp) + ((size_t)n << 9) + co) = ov;
}

extern "C" void kernel_launch(void* const* d_in, const int* in_sizes, int n_in,
                              void* d_out, int out_size, void* d_ws, size_t ws_size,
                              hipStream_t stream) {
  float* out = (float*)d_out;  // confirmed: f32 in / f32 out
  if (ws_size < ((size_t)80 << 20)) {
    ws_bad_kernel<<<1, 64, 0, stream>>>(out);  // sentinel 5000
    return;
  }

  const float* x = (const float*)d_in[0];

  char* ws = (char*)d_ws;
  float*          xs = (float*)ws;                                       // 0-16 MB
  __hip_bfloat16* t0 = (__hip_bfloat16*)(ws + ((size_t)16 << 20));       // 16-24 MB
  __hip_bfloat16* t1 = (__hip_bfloat16*)(ws + ((size_t)24 << 20));       // 24-48 MB
  __hip_bfloat16* t2 = (__hip_bfloat16*)(ws + ((size_t)56 << 20));       // 56-64 MB
  __hip_bfloat16* wc = (__hip_bfloat16*)(ws + ((size_t)64 << 20));       // 64-76 MB
  __hip_bfloat16* vT = t1 + (size_t)NTOK * 1536;                         // 48-56 MB

  __hip_bfloat16* wc_ff1_w1 = wc + 0;
  __hip_bfloat16* wc_ff1_w2 = wc + 1048576;
  __hip_bfloat16* wc_qkv_w  = wc + 2097152;
  __hip_bfloat16* wc_out_w  = wc + 2883584;
  __hip_bfloat16* wc_pw1_w  = wc + 3145728;
  __hip_bfloat16* wc_pw2_w  = wc + 3670016;
  __hip_bfloat16* wc_ff2_w1 = wc + 3932160;
  __hip_bfloat16* wc_ff2_w2 = wc + 4980736;
  __hip_bfloat16* wc_dwT    = wc + 6029312;      // [31][512] bf16 transposed
  __hip_bfloat16* sm        = wc + 6045184;
  __hip_bfloat16* c_ln1_g = sm + 0,     *c_ln1_b = sm + 512,   *c_ff1_b1 = sm + 1024;
  __hip_bfloat16* c_ff1_b2 = sm + 3072, *c_lna_g = sm + 3584,  *c_lna_b = sm + 4096;
  __hip_bfloat16* c_qkv_b = sm + 4608,  *c_out_b = sm + 6144,  *c_lnc_g = sm + 6656;
  __hip_bfloat16* c_lnc_b = sm + 7168,  *c_pw1_b = sm + 7680,  *c_dw_b = sm + 8704;
  __hip_bfloat16* c_bn_g = sm + 9216,   *c_bn_b = sm + 9728,   *c_bn_m = sm + 10240;
  __hip_bfloat16* c_bn_v = sm + 10752,  *c_pw2_b = sm + 11264, *c_ln2_g = sm + 11776;
  __hip_bfloat16* c_ln2_b = sm + 12288, *c_ff2_b1 = sm + 12800, *c_ff2_b2 = sm + 14848;
  __hip_bfloat16* c_lnf_g = sm + 15360, *c_lnf_b = sm + 15872;

  // --- input normalization (f32 world) ---
  {
    WPack wp;
    wp.s[0] = {(const float*)d_in[3],  0,      131072};  // ff1_w1
    wp.s[1] = {(const float*)d_in[5],  131072, 131072};  // ff1_w2
    wp.s[2] = {(const float*)d_in[9],  262144, 98304};   // qkv_w
    wp.s[3] = {(const float*)d_in[11], 360448, 32768};   // out_w
    wp.s[4] = {(const float*)d_in[15], 393216, 65536};   // pw1_w
    wp.s[5] = {(const float*)d_in[23], 458752, 32768};   // pw2_w
    wp.s[6] = {(const float*)d_in[27], 491520, 131072};  // ff2_w1
    wp.s[7] = {(const float*)d_in[29], 622592, 131072};  // ff2_w2
    cast_wall_kernel<<<2944, 256, 0, stream>>>(wp, wc);
  }
  cast_dww_kernel<<<1, 256, 0, stream>>>((const float*)d_in[17], wc_dwT);
  PtrPack pk;
  const int small_idx[23] = {1, 2, 4, 6, 7, 8, 10, 12, 13, 14, 16, 18,
                             19, 20, 21, 22, 24, 25, 26, 28, 30, 31, 32};
  for (int t = 0; t < 23; ++t) pk.p[t] = d_in[small_idx[t]];
  cast_small_kernel<<<1, 256, 0, stream>>>(pk, sm);

  // --- FF1 (half-scale): xs = 1.5*x + 0.5*(silu(ln(x)@w1)@w2 + b2) ---
  ln_kernel<<<2048, 256, 0, stream>>>(x, c_ln1_g, c_ln1_b, t0);
  gemm_bt<1><<<dim3(64, 16), 256, 0, stream>>>(t0, wc_ff1_w1, c_ff1_b1, t1, nullptr, nullptr, 512, 2048, 0.f, 0.f);
  gemm64_resid<<<dim3(128, 4), 256, 0, stream>>>(t1, wc_ff1_w2, c_ff1_b2, x, xs, 2048, 1.5f, 0.5f);

  // --- Attention (qkv GEMM with fused V-transpose; MFMA flash v6) ---
  ln_kernel<<<2048, 256, 0, stream>>>(xs, c_lna_g, c_lna_b, t0);
  gemm_bt<3><<<dim3(64, 12), 256, 0, stream>>>(t0, wc_qkv_w, c_qkv_b, t1, nullptr, vT, 512, 1536, 0.f, 0.f);
  attn_kernel<<<512, 256, 0, stream>>>(t1, vT, t2);
  gemm64_resid<<<dim3(128, 4), 256, 0, stream>>>(t2, wc_out_w, c_out_b, xs, xs, 512, 1.0f, 1.0f);

  // --- Conv module ---
  ln_kernel<<<2048, 256, 0, stream>>>(xs, c_lnc_g, c_lnc_b, t0);
  gemm_bt<0><<<dim3(64, 8), 256, 0, stream>>>(t0, wc_pw1_w, c_pw1_b, t1, nullptr, nullptr, 512, 1024, 0.f, 0.f);
  glu8_kernel<<<2048, 256, 0, stream>>>(t1, t2);
  dwconv8_kernel<<<2048, 256, 0, stream>>>(t2, wc_dwT, c_dw_b, c_bn_g, c_bn_b, c_bn_m, c_bn_v, t0);
  gemm64_resid<<<dim3(128, 4), 256, 0, stream>>>(t0, wc_pw2_w, c_pw2_b, xs, xs, 512, 2.0f, 1.0f);

  // --- FF2 (half-scale) ---
  ln_kernel<<<2048, 256, 0, stream>>>(xs, c_ln2_g, c_ln2_b, t0);
  gemm_bt<1><<<dim3(64, 16), 256, 0, stream>>>(t0, wc_ff2_w1, c_ff2_b1, t1, nullptr, nullptr, 512, 2048, 0.f, 0.f);
  gemm64_resid<<<dim3(128, 4), 256, 0, stream>>>(t1, wc_ff2_w2, c_ff2_b2, xs, xs, 2048, 1.5f, 0.5f);

  // --- Final LN -> FP32 out ---
  lnf_kernel<<<2048, 256, 0, stream>>>(xs, c_lnf_g, c_lnf_b, out);
}

// Round 19
// 295.801 us; speedup vs baseline: 1.0490x; 1.0214x over previous
//
#include <hip/hip_runtime.h>
#include <hip/hip_bf16.h>

typedef __attribute__((ext_vector_type(8))) short bf16x8;
typedef __attribute__((ext_vector_type(4))) short bf16x4;
typedef __attribute__((ext_vector_type(4))) float f32x4;

#define NTOK 8192
#define SEQ  1024
#define NH   8

__device__ __forceinline__ float bfs2f(short s) {
  union { unsigned u; float f; } x; x.u = ((unsigned)(unsigned short)s) << 16; return x.f;
}
__device__ __forceinline__ short f2bfs(float f) {
  __hip_bfloat16 h = __float2bfloat16(f);
  return *reinterpret_cast<short*>(&h);
}
__device__ __forceinline__ float bfp2f(const __hip_bfloat16* p) {
  return bfs2f(*reinterpret_cast<const short*>(p));
}

__device__ __forceinline__ void gld16(const void* g, void* l) {
  __builtin_amdgcn_global_load_lds(
      (__attribute__((address_space(1))) void*)const_cast<void*>(g),
      (__attribute__((address_space(3))) void*)l, 16, 0, 0);
}

// ---------------- fused f32 weight -> bf16 cast (all big tensors, 1 launch) ------
struct WSeg { const float* src; unsigned dst_off; unsigned nvec; };
struct WPack { WSeg s[8]; };

__global__ __launch_bounds__(256) void cast_wall_kernel(WPack p,
                                                        __hip_bfloat16* __restrict__ dst) {
  unsigned v = blockIdx.x * 256 + threadIdx.x;
#pragma unroll
  for (int t = 0; t < 8; ++t) {
    if (v < p.s[t].nvec) {
      const float* s = p.s[t].src + (size_t)v * 8;
      f32x4 a = *reinterpret_cast<const f32x4*>(s);
      f32x4 b = *reinterpret_cast<const f32x4*>(s + 4);
      bf16x8 o;
#pragma unroll
      for (int j = 0; j < 4; ++j) { o[j] = f2bfs(a[j]); o[4 + j] = f2bfs(b[j]); }
      *reinterpret_cast<bf16x8*>(reinterpret_cast<short*>(dst) +
                                 (size_t)(p.s[t].dst_off + v) * 8) = o;
      return;
    }
    v -= p.s[t].nvec;
  }
}

// ---------------- dw_w f32 [512][31] -> bf16 transposed [31][512] ----------------
__global__ __launch_bounds__(256) void cast_dww_kernel(const float* __restrict__ src,
                                                       __hip_bfloat16* __restrict__ dst) {
  for (int k = 0; k < 31; ++k)
    for (int c = threadIdx.x; c < 512; c += 256)
      dst[k * 512 + c] = __float2bfloat16(src[c * 31 + k]);
}

struct PtrPack { const void* p[23]; };

__global__ __launch_bounds__(256) void cast_small_kernel(PtrPack pk,
                                                         __hip_bfloat16* __restrict__ dst) {
  constexpr int sizes[23] = {512, 512, 2048, 512, 512, 512, 1536, 512, 512, 512, 1024, 512,
                             512, 512, 512, 512, 512, 512, 512, 2048, 512, 512, 512};
  int off = 0;
  for (int t = 0; t < 23; ++t) {
    const int n = sizes[t];
    for (int i = threadIdx.x; i < n; i += 256)
      dst[off + i] = __float2bfloat16(((const float*)pk.p[t])[i]);
    off += n;
  }
}

__global__ void ws_bad_kernel(float* __restrict__ out) {
  if (threadIdx.x == 0) out[0] = 5000.f;
}

// ---------------- LayerNorm: bf16 stream in -> bf16 out (D=512) ----------------
__global__ __launch_bounds__(256) void lnb_kernel(const __hip_bfloat16* __restrict__ in,
                                                  const __hip_bfloat16* __restrict__ g,
                                                  const __hip_bfloat16* __restrict__ b,
                                                  __hip_bfloat16* __restrict__ out) {
  const int wv = threadIdx.x >> 6, ln = threadIdx.x & 63;
  const int row = blockIdx.x * 4 + wv;
  bf16x8 iv = *reinterpret_cast<const bf16x8*>(in + (size_t)row * 512 + ln * 8);
  float v[8];
#pragma unroll
  for (int j = 0; j < 8; ++j) v[j] = bfs2f(iv[j]);
  float s = 0.f;
#pragma unroll
  for (int j = 0; j < 8; ++j) s += v[j];
  for (int m = 1; m < 64; m <<= 1) s += __shfl_xor(s, m);
  const float mean = s * (1.f / 512.f);
  float q = 0.f;
#pragma unroll
  for (int j = 0; j < 8; ++j) { float d = v[j] - mean; q += d * d; }
  for (int m = 1; m < 64; m <<= 1) q += __shfl_xor(q, m);
  const float rstd = rsqrtf(q * (1.f / 512.f) + 1e-5f);
  bf16x8 gg = *reinterpret_cast<const bf16x8*>(g + ln * 8);
  bf16x8 bb = *reinterpret_cast<const bf16x8*>(b + ln * 8);
  bf16x8 ov;
#pragma unroll
  for (int j = 0; j < 8; ++j)
    ov[j] = f2bfs((v[j] - mean) * rstd * bfs2f(gg[j]) + bfs2f(bb[j]));
  *reinterpret_cast<bf16x8*>(out + (size_t)row * 512 + ln * 8) = ov;
}

// ---------------- LayerNorm: fp32 in -> bf16 out (first LN reads x) --------------
__global__ __launch_bounds__(256) void ln_kernel(const float* __restrict__ in,
                                                 const __hip_bfloat16* __restrict__ g,
                                                 const __hip_bfloat16* __restrict__ b,
                                                 __hip_bfloat16* __restrict__ out) {
  const int wv = threadIdx.x >> 6, ln = threadIdx.x & 63;
  const int row = blockIdx.x * 4 + wv;
  const float* p = in + (size_t)row * 512 + ln * 8;
  float v[8];
  {
    const f32x4* p4 = reinterpret_cast<const f32x4*>(p);
    f32x4 a = p4[0], c = p4[1];
#pragma unroll
    for (int j = 0; j < 4; ++j) { v[j] = a[j]; v[4 + j] = c[j]; }
  }
  float s = 0.f;
#pragma unroll
  for (int j = 0; j < 8; ++j) s += v[j];
  for (int m = 1; m < 64; m <<= 1) s += __shfl_xor(s, m);
  const float mean = s * (1.f / 512.f);
  float q = 0.f;
#pragma unroll
  for (int j = 0; j < 8; ++j) { float d = v[j] - mean; q += d * d; }
  for (int m = 1; m < 64; m <<= 1) q += __shfl_xor(q, m);
  const float rstd = rsqrtf(q * (1.f / 512.f) + 1e-5f);
  bf16x8 gg = *reinterpret_cast<const bf16x8*>(g + ln * 8);
  bf16x8 bb = *reinterpret_cast<const bf16x8*>(b + ln * 8);
  bf16x8 ov;
#pragma unroll
  for (int j = 0; j < 8; ++j)
    ov[j] = f2bfs((v[j] - mean) * rstd * bfs2f(gg[j]) + bfs2f(bb[j]));
  *reinterpret_cast<bf16x8*>(out + (size_t)row * 512 + ln * 8) = ov;
}

// ---------------- final LayerNorm: bf16 stream in -> FP32 out --------------------
__global__ __launch_bounds__(256) void lnf_kernel(const __hip_bfloat16* __restrict__ in,
                                                  const __hip_bfloat16* __restrict__ g,
                                                  const __hip_bfloat16* __restrict__ b,
                                                  float* __restrict__ out) {
  const int wv = threadIdx.x >> 6, ln = threadIdx.x & 63;
  const int row = blockIdx.x * 4 + wv;
  bf16x8 iv = *reinterpret_cast<const bf16x8*>(in + (size_t)row * 512 + ln * 8);
  float v[8];
#pragma unroll
  for (int j = 0; j < 8; ++j) v[j] = bfs2f(iv[j]);
  float s = 0.f;
#pragma unroll
  for (int j = 0; j < 8; ++j) s += v[j];
  for (int m = 1; m < 64; m <<= 1) s += __shfl_xor(s, m);
  const float mean = s * (1.f / 512.f);
  float q = 0.f;
#pragma unroll
  for (int j = 0; j < 8; ++j) { float d = v[j] - mean; q += d * d; }
  for (int m = 1; m < 64; m <<= 1) q += __shfl_xor(q, m);
  const float rstd = rsqrtf(q * (1.f / 512.f) + 1e-5f);
  bf16x8 gg = *reinterpret_cast<const bf16x8*>(g + ln * 8);
  bf16x8 bb = *reinterpret_cast<const bf16x8*>(b + ln * 8);
  f32x4 o0, o1;
#pragma unroll
  for (int j = 0; j < 4; ++j) {
    o0[j] = (v[j] - mean) * rstd * bfs2f(gg[j]) + bfs2f(bb[j]);
    o1[j] = (v[4 + j] - mean) * rstd * bfs2f(gg[4 + j]) + bfs2f(bb[4 + j]);
  }
  float* op = out + (size_t)row * 512 + ln * 8;
  *reinterpret_cast<f32x4*>(op) = o0;
  *reinterpret_cast<f32x4*>(op + 4) = o1;
}

// ---------------- MFMA GEMM (m97 + T2 swizzle, XCD-swizzled, 3 blocks/CU) --------
// EPI 0: bf16 out ; EPI 1: bf16 silu ;
// EPI 3: qkv — Q/K to outb, V written TRANSPOSED to vTout[b,h,d,s] (short4).
template <int EPI>
__global__ __launch_bounds__(256, 3) void gemm_bt(const __hip_bfloat16* __restrict__ A,
                                                  const __hip_bfloat16* __restrict__ W,
                                                  const __hip_bfloat16* __restrict__ bias,
                                                  __hip_bfloat16* __restrict__ outb,
                                                  __hip_bfloat16* __restrict__ vTout,
                                                  int K, int M) {
  __shared__ __align__(16) __hip_bfloat16 As[128 * 64];
  __shared__ __align__(16) __hip_bfloat16 Bs[128 * 64];
  const int tid = threadIdx.x;
  const int wv = tid >> 6, ln = tid & 63;
  const int hi = ln >> 4, lo = ln & 15;
  const int lo7 = lo & 7;
  const int gx = gridDim.x;
  const int nwg = gx * gridDim.y;
  const int t = blockIdx.y * gx + blockIdx.x;
  const int w = (t & 7) * (nwg >> 3) + (t >> 3);
  const int n0 = (w & (gx - 1)) * 128;
  const int m0 = (w / gx) * 128;
  const int wr = wv >> 1, wc = wv & 1;
  const int srow = ln >> 3;
  const int scolz = (((ln & 7) ^ srow) << 3);   // swizzled source granule

  f32x4 acc[4][4] = {};

  for (int k0 = 0; k0 < K; k0 += 64) {
    __syncthreads();
#pragma unroll
    for (int i = 0; i < 4; ++i) {
      const int grp = i * 4 + wv;
      const int row = grp * 8 + srow;
      gld16(A + (size_t)(n0 + row) * K + k0 + scolz, As + grp * 512);
      gld16(W + (size_t)(m0 + row) * K + k0 + scolz, Bs + grp * 512);
    }
    __syncthreads();
#pragma unroll
    for (int kk2 = 0; kk2 < 2; ++kk2) {
      const int g0 = ((kk2 * 4 + hi) ^ lo7) << 3;   // swizzled read granule
      bf16x8 af[4], bfr[4];
#pragma unroll
      for (int r = 0; r < 4; ++r)
        af[r] = *reinterpret_cast<const bf16x8*>(As + (wr * 64 + r * 16 + lo) * 64 + g0);
#pragma unroll
      for (int c = 0; c < 4; ++c)
        bfr[c] = *reinterpret_cast<const bf16x8*>(Bs + (wc * 64 + c * 16 + lo) * 64 + g0);
#pragma unroll
      for (int r = 0; r < 4; ++r)
#pragma unroll
        for (int c = 0; c < 4; ++c)
          acc[r][c] = __builtin_amdgcn_mfma_f32_16x16x32_bf16(af[r], bfr[c], acc[r][c], 0, 0, 0);
    }
  }

#pragma unroll
  for (int r = 0; r < 4; ++r) {
#pragma unroll
    for (int c = 0; c < 4; ++c) {
      const int m = m0 + wc * 64 + c * 16 + lo;
      const float bv = bfp2f(bias + m);
      const int nb = n0 + wr * 64 + r * 16 + hi * 4;
      if constexpr (EPI == 3) {
        if (m >= 1024) {  // V part -> transposed store
          const int hd = m - 1024;
          __hip_bfloat16* vp = vTout +
              ((size_t)((nb >> 10) * NH + (hd >> 6)) * 64 + (hd & 63)) * 1024 + (nb & 1023);
          bf16x4 vv;
#pragma unroll
          for (int j = 0; j < 4; ++j) vv[j] = f2bfs(acc[r][c][j] + bv);
          *reinterpret_cast<bf16x4*>(vp) = vv;
          continue;
        }
      }
#pragma unroll
      for (int j = 0; j < 4; ++j) {
        const int n = nb + j;
        float v = acc[r][c][j] + bv;
        if constexpr (EPI == 1) v = v / (1.f + __expf(-v));
        outb[(size_t)n * M + m] = __float2bfloat16(v);
      }
    }
  }
}

// ---------------- MFMA GEMM, M=512 resid: BM=64 x BN=128 + T2 swizzle ------------
// resid(bf16)[idx] = alpha*rsrc[idx] + beta*(A@W^T + bias); rsrc f32 (RF32) or bf16.
template <int RF32>
__global__ __launch_bounds__(256, 4) void gemm64_resid(const __hip_bfloat16* __restrict__ A,
                                                       const __hip_bfloat16* __restrict__ W,
                                                       const __hip_bfloat16* __restrict__ bias,
                                                       const void* __restrict__ rsrc,
                                                       __hip_bfloat16* __restrict__ resid,
                                                       int K, float alpha, float beta) {
  __shared__ __align__(16) __hip_bfloat16 As[64 * 64];
  __shared__ __align__(16) __hip_bfloat16 Bs[128 * 64];
  const int tid = threadIdx.x;
  const int wv = tid >> 6, ln = tid & 63;
  const int hi = ln >> 4, lo = ln & 15;
  const int lo7 = lo & 7;
  const int gx = gridDim.x;
  const int nwg = gx * gridDim.y;
  const int t = blockIdx.y * gx + blockIdx.x;
  const int w = (t & 7) * (nwg >> 3) + (t >> 3);
  const int n0 = (w & (gx - 1)) * 64;
  const int m0 = (w / gx) * 128;
  const int wr = wv >> 1, wc = wv & 1;
  const int srow = ln >> 3;
  const int scolz = (((ln & 7) ^ srow) << 3);

  f32x4 acc[2][4] = {};

  for (int k0 = 0; k0 < K; k0 += 64) {
    __syncthreads();
#pragma unroll
    for (int i = 0; i < 2; ++i) {
      const int grp = i * 4 + wv;
      gld16(A + (size_t)(n0 + grp * 8 + srow) * K + k0 + scolz, As + grp * 512);
    }
#pragma unroll
    for (int i = 0; i < 4; ++i) {
      const int grp = i * 4 + wv;
      gld16(W + (size_t)(m0 + grp * 8 + srow) * K + k0 + scolz, Bs + grp * 512);
    }
    __syncthreads();
#pragma unroll
    for (int kk2 = 0; kk2 < 2; ++kk2) {
      const int g0 = ((kk2 * 4 + hi) ^ lo7) << 3;
      bf16x8 af[2], bfr[4];
#pragma unroll
      for (int r = 0; r < 2; ++r)
        af[r] = *reinterpret_cast<const bf16x8*>(As + (wr * 32 + r * 16 + lo) * 64 + g0);
#pragma unroll
      for (int c = 0; c < 4; ++c)
        bfr[c] = *reinterpret_cast<const bf16x8*>(Bs + (wc * 64 + c * 16 + lo) * 64 + g0);
#pragma unroll
      for (int r = 0; r < 2; ++r)
#pragma unroll
        for (int c = 0; c < 4; ++c)
          acc[r][c] = __builtin_amdgcn_mfma_f32_16x16x32_bf16(af[r], bfr[c], acc[r][c], 0, 0, 0);
    }
  }

#pragma unroll
  for (int r = 0; r < 2; ++r) {
#pragma unroll
    for (int c = 0; c < 4; ++c) {
      const int m = m0 + wc * 64 + c * 16 + lo;
      const float bv = bfp2f(bias + m);
#pragma unroll
      for (int j = 0; j < 4; ++j) {
        const int n = n0 + wr * 32 + r * 16 + hi * 4 + j;
        const size_t idx = (size_t)n * 512 + m;
        const float rv = RF32 ? ((const float*)rsrc)[idx]
                              : bfs2f(((const short*)rsrc)[idx]);
        resid[idx] = __float2bfloat16(alpha * rv + beta * (acc[r][c][j] + bv));
      }
    }
  }
}

// ---------------- MFMA flash attention v6: 2 q-tiles/wave, K/V frag reuse --------
__global__ __launch_bounds__(256, 2) void attn_kernel(const __hip_bfloat16* __restrict__ qkv,
                                                      const __hip_bfloat16* __restrict__ vT,
                                                      __hip_bfloat16* __restrict__ ctx) {
  __shared__ __align__(16) short Ks[2][64 * 64];
  __shared__ __align__(16) short Vs[2][64 * 64];
  __shared__ __align__(16) short P[4][16][64];
  const int tid = threadIdx.x;
  const int wv = tid >> 6, ln = tid & 63;
  const int hi = ln >> 4, lo = ln & 15;
  const int lo7 = lo & 7;
  const int blk = ((blockIdx.x & 7) << 6) | (blockIdx.x >> 3);
  const int qt = blk & 7, h = (blk >> 3) & 7, b = blk >> 6;
  const int q0 = qt * 128 + wv * 16;   // tile A rows; tile B = q0 + 64

  const int srow8 = ln >> 3;
  const int gsrc = (ln & 7) ^ srow8;

  bf16x8 aq0a, aq1a, aq0b, aq1b;
  {
    const __hip_bfloat16* qpa = qkv + (size_t)(b * SEQ + q0 + lo) * 1536 + h * 64 + hi * 8;
    const __hip_bfloat16* qpb = qpa + (size_t)64 * 1536;
    bf16x8 r0 = *reinterpret_cast<const bf16x8*>(qpa);
    bf16x8 r1 = *reinterpret_cast<const bf16x8*>(qpa + 32);
    bf16x8 r2 = *reinterpret_cast<const bf16x8*>(qpb);
    bf16x8 r3 = *reinterpret_cast<const bf16x8*>(qpb + 32);
#pragma unroll
    for (int j = 0; j < 8; ++j) {
      aq0a[j] = f2bfs(bfs2f(r0[j]) * 0.125f);
      aq1a[j] = f2bfs(bfs2f(r1[j]) * 0.125f);
      aq0b[j] = f2bfs(bfs2f(r2[j]) * 0.125f);
      aq1b[j] = f2bfs(bfs2f(r3[j]) * 0.125f);
    }
  }

  const __hip_bfloat16* kbase = qkv + 512 + h * 64 + (size_t)b * SEQ * 1536;
  const __hip_bfloat16* vbase = vT + (size_t)(b * NH + h) * 64 * 1024;

  f32x4 oaccA[4] = {}, oaccB[4] = {};
  float lrowA[4] = {0.f, 0.f, 0.f, 0.f};
  float lrowB[4] = {0.f, 0.f, 0.f, 0.f};

#pragma unroll
  for (int c = 0; c < 2; ++c) {
    const int r = c * 32 + wv * 8 + srow8;
    gld16(kbase + (size_t)r * 1536 + gsrc * 8, &Ks[0][(c * 32 + wv * 8) * 64]);
    gld16(vbase + (size_t)r * 1024 + gsrc * 8, &Vs[0][(c * 32 + wv * 8) * 64]);
  }
  __syncthreads();

  int cb = 0;
  for (int kt = 0; kt < 16; ++kt) {
    if (kt < 15) {
      const int kb2 = (kt + 1) * 64;
#pragma unroll
      for (int c = 0; c < 2; ++c) {
        const int r = c * 32 + wv * 8 + srow8;
        gld16(kbase + (size_t)(kb2 + r) * 1536 + gsrc * 8,
              &Ks[cb ^ 1][(c * 32 + wv * 8) * 64]);
        gld16(vbase + (size_t)r * 1024 + kb2 + gsrc * 8,
              &Vs[cb ^ 1][(c * 32 + wv * 8) * 64]);
      }
    }

    bf16x8 bk0[4], bk1[4];
#pragma unroll
    for (int nt = 0; nt < 4; ++nt) {
      const short* kr = &Ks[cb][(nt * 16 + lo) * 64];
      bk0[nt] = *reinterpret_cast<const bf16x8*>(kr + ((hi ^ lo7) << 3));
      bk1[nt] = *reinterpret_cast<const bf16x8*>(kr + (((hi + 4) ^ lo7) << 3));
    }
    f32x4 scA[4] = {}, scB[4] = {};
#pragma unroll
    for (int nt = 0; nt < 4; ++nt) {
      scA[nt] = __builtin_amdgcn_mfma_f32_16x16x32_bf16(aq0a, bk0[nt], scA[nt], 0, 0, 0);
      scA[nt] = __builtin_amdgcn_mfma_f32_16x16x32_bf16(aq1a, bk1[nt], scA[nt], 0, 0, 0);
      scB[nt] = __builtin_amdgcn_mfma_f32_16x16x32_bf16(aq0b, bk0[nt], scB[nt], 0, 0, 0);
      scB[nt] = __builtin_amdgcn_mfma_f32_16x16x32_bf16(aq1b, bk1[nt], scB[nt], 0, 0, 0);
    }

    bf16x8 bv0[4], bv1[4];
#pragma unroll
    for (int dt = 0; dt < 4; ++dt) {
      const short* vr = &Vs[cb][(dt * 16 + lo) * 64];
      bv0[dt] = *reinterpret_cast<const bf16x8*>(vr + ((hi ^ lo7) << 3));
      bv1[dt] = *reinterpret_cast<const bf16x8*>(vr + (((hi + 4) ^ lo7) << 3));
    }

#pragma unroll
    for (int j = 0; j < 4; ++j) {
      const int prow = hi * 4 + j;
      const int pswz = (prow & 7) << 3;
#pragma unroll
      for (int nt = 0; nt < 4; ++nt) {
        const float p = __expf(scA[nt][j]);
        P[wv][prow][(nt * 16 + lo) ^ pswz] = f2bfs(p);
        lrowA[j] += p;
      }
    }
    asm volatile("" ::: "memory");
    {
      const short* pr = &P[wv][lo][0];
      bf16x8 ap0 = *reinterpret_cast<const bf16x8*>(pr + ((hi ^ lo7) << 3));
      bf16x8 ap1 = *reinterpret_cast<const bf16x8*>(pr + (((hi + 4) ^ lo7) << 3));
#pragma unroll
      for (int dt = 0; dt < 4; ++dt) {
        oaccA[dt] = __builtin_amdgcn_mfma_f32_16x16x32_bf16(ap0, bv0[dt], oaccA[dt], 0, 0, 0);
        oaccA[dt] = __builtin_amdgcn_mfma_f32_16x16x32_bf16(ap1, bv1[dt], oaccA[dt], 0, 0, 0);
      }
    }
    asm volatile("" ::: "memory");

#pragma unroll
    for (int j = 0; j < 4; ++j) {
      const int prow = hi * 4 + j;
      const int pswz = (prow & 7) << 3;
#pragma unroll
      for (int nt = 0; nt < 4; ++nt) {
        const float p = __expf(scB[nt][j]);
        P[wv][prow][(nt * 16 + lo) ^ pswz] = f2bfs(p);
        lrowB[j] += p;
      }
    }
    asm volatile("" ::: "memory");
    {
      const short* pr = &P[wv][lo][0];
      bf16x8 ap0 = *reinterpret_cast<const bf16x8*>(pr + ((hi ^ lo7) << 3));
      bf16x8 ap1 = *reinterpret_cast<const bf16x8*>(pr + (((hi + 4) ^ lo7) << 3));
#pragma unroll
      for (int dt = 0; dt < 4; ++dt) {
        oaccB[dt] = __builtin_amdgcn_mfma_f32_16x16x32_bf16(ap0, bv0[dt], oaccB[dt], 0, 0, 0);
        oaccB[dt] = __builtin_amdgcn_mfma_f32_16x16x32_bf16(ap1, bv1[dt], oaccB[dt], 0, 0, 0);
      }
    }
    __syncthreads();
    cb ^= 1;
  }

#pragma unroll
  for (int j = 0; j < 4; ++j) {
    float sa = lrowA[j], sb = lrowB[j];
    sa += __shfl_xor(sa, 1); sb += __shfl_xor(sb, 1);
    sa += __shfl_xor(sa, 2); sb += __shfl_xor(sb, 2);
    sa += __shfl_xor(sa, 4); sb += __shfl_xor(sb, 4);
    sa += __shfl_xor(sa, 8); sb += __shfl_xor(sb, 8);
    lrowA[j] = sa; lrowB[j] = sb;
  }

#pragma unroll
  for (int dt = 0; dt < 4; ++dt)
#pragma unroll
    for (int j = 0; j < 4; ++j) {
      const int d = h * 64 + dt * 16 + lo;
      const int na = b * SEQ + q0 + hi * 4 + j;
      ctx[(size_t)na * 512 + d] = __float2bfloat16(oaccA[dt][j] / lrowA[j]);
      const int nb = na + 64;
      ctx[(size_t)nb * 512 + d] = __float2bfloat16(oaccB[dt][j] / lrowB[j]);
    }
}

// ---------------- GLU, 8 channels/thread ----------------
__global__ __launch_bounds__(256) void glu8_kernel(const __hip_bfloat16* __restrict__ y,
                                                   __hip_bfloat16* __restrict__ o) {
  const int i = blockIdx.x * 256 + threadIdx.x;
  const int c8 = i & 63;
  const int n = i >> 6;
  const short* yp = reinterpret_cast<const short*>(y) + (size_t)n * 1024 + c8 * 8;
  bf16x8 a = *reinterpret_cast<const bf16x8*>(yp);
  bf16x8 g = *reinterpret_cast<const bf16x8*>(yp + 512);
  bf16x8 ov;
#pragma unroll
  for (int j = 0; j < 8; ++j) {
    const float av = bfs2f(a[j]);
    const float gv = bfs2f(g[j]);
    ov[j] = f2bfs(av / (1.f + __expf(-gv)));
  }
  *reinterpret_cast<bf16x8*>(reinterpret_cast<short*>(o) + (size_t)n * 512 + c8 * 8) = ov;
}

// ---------------- depthwise conv K=31 + BN + SiLU, bf16 in, 8 ch/thread ----------
__global__ __launch_bounds__(256) void dwconv8_kernel(const __hip_bfloat16* __restrict__ cin,
                                                      const __hip_bfloat16* __restrict__ wkT,
                                                      const __hip_bfloat16* __restrict__ cb,
                                                      const __hip_bfloat16* __restrict__ bng,
                                                      const __hip_bfloat16* __restrict__ bnb,
                                                      const __hip_bfloat16* __restrict__ bnm,
                                                      const __hip_bfloat16* __restrict__ bnv,
                                                      __hip_bfloat16* __restrict__ outp) {
  const int i = blockIdx.x * 256 + threadIdx.x;
  const int c8 = i & 63;
  const int n = i >> 6;
  const int t = n & 1023;
  const int base = n - t;
  const int co = c8 * 8;

  float acc[8];
  {
    bf16x8 bv = *reinterpret_cast<const bf16x8*>(cb + co);
#pragma unroll
    for (int j = 0; j < 8; ++j) acc[j] = bfs2f(bv[j]);
  }
  const int k0 = (t >= 15) ? 0 : (15 - t);
  const int k1 = (t <= SEQ - 16) ? 31 : (SEQ - 1 - t + 16);
  const short* cin_s = reinterpret_cast<const short*>(cin);
  const short* wk_s = reinterpret_cast<const short*>(wkT);
  for (int k = k0; k < k1; ++k) {
    const int ts = t + k - 15;
    bf16x8 xv = *reinterpret_cast<const bf16x8*>(cin_s + (((size_t)(base + ts)) << 9) + co);
    bf16x8 wv = *reinterpret_cast<const bf16x8*>(wk_s + k * 512 + co);
#pragma unroll
    for (int j = 0; j < 8; ++j) acc[j] += bfs2f(xv[j]) * bfs2f(wv[j]);
  }
  bf16x8 g = *reinterpret_cast<const bf16x8*>(bng + co);
  bf16x8 bb = *reinterpret_cast<const bf16x8*>(bnb + co);
  bf16x8 bm = *reinterpret_cast<const bf16x8*>(bnm + co);
  bf16x8 bvv = *reinterpret_cast<const bf16x8*>(bnv + co);
  bf16x8 ov;
#pragma unroll
  for (int j = 0; j < 8; ++j) {
    const float scl = bfs2f(g[j]) * rsqrtf(bfs2f(bvv[j]) + 1e-5f);
    float v = (acc[j] - bfs2f(bm[j])) * scl + bfs2f(bb[j]);
    v = v / (1.f + __expf(-v));
    ov[j] = f2bfs(v);
  }
  *reinterpret_cast<bf16x8*>(reinterpret_cast<short*>(outp) + ((size_t)n << 9) + co) = ov;
}

extern "C" void kernel_launch(void* const* d_in, const int* in_sizes, int n_in,
                              void* d_out, int out_size, void* d_ws, size_t ws_size,
                              hipStream_t stream) {
  float* out = (float*)d_out;  // confirmed: f32 in / f32 out
  if (ws_size < ((size_t)80 << 20)) {
    ws_bad_kernel<<<1, 64, 0, stream>>>(out);  // sentinel 5000
    return;
  }

  const float* x = (const float*)d_in[0];

  char* ws = (char*)d_ws;
  __hip_bfloat16* xsb = (__hip_bfloat16*)ws;                             // 0-8 MB bf16 stream
  __hip_bfloat16* t0 = (__hip_bfloat16*)(ws + ((size_t)16 << 20));       // 16-24 MB
  __hip_bfloat16* t1 = (__hip_bfloat16*)(ws + ((size_t)24 << 20));       // 24-48 MB
  __hip_bfloat16* t2 = (__hip_bfloat16*)(ws + ((size_t)56 << 20));       // 56-64 MB
  __hip_bfloat16* wc = (__hip_bfloat16*)(ws + ((size_t)64 << 20));       // 64-76 MB
  __hip_bfloat16* vT = t1 + (size_t)NTOK * 1536;                         // 48-56 MB

  __hip_bfloat16* wc_ff1_w1 = wc + 0;
  __hip_bfloat16* wc_ff1_w2 = wc + 1048576;
  __hip_bfloat16* wc_qkv_w  = wc + 2097152;
  __hip_bfloat16* wc_out_w  = wc + 2883584;
  __hip_bfloat16* wc_pw1_w  = wc + 3145728;
  __hip_bfloat16* wc_pw2_w  = wc + 3670016;
  __hip_bfloat16* wc_ff2_w1 = wc + 3932160;
  __hip_bfloat16* wc_ff2_w2 = wc + 4980736;
  __hip_bfloat16* wc_dwT    = wc + 6029312;      // [31][512] bf16 transposed
  __hip_bfloat16* sm        = wc + 6045184;
  __hip_bfloat16* c_ln1_g = sm + 0,     *c_ln1_b = sm + 512,   *c_ff1_b1 = sm + 1024;
  __hip_bfloat16* c_ff1_b2 = sm + 3072, *c_lna_g = sm + 3584,  *c_lna_b = sm + 4096;
  __hip_bfloat16* c_qkv_b = sm + 4608,  *c_out_b = sm + 6144,  *c_lnc_g = sm + 6656;
  __hip_bfloat16* c_lnc_b = sm + 7168,  *c_pw1_b = sm + 7680,  *c_dw_b = sm + 8704;
  __hip_bfloat16* c_bn_g = sm + 9216,   *c_bn_b = sm + 9728,   *c_bn_m = sm + 10240;
  __hip_bfloat16* c_bn_v = sm + 10752,  *c_pw2_b = sm + 11264, *c_ln2_g = sm + 11776;
  __hip_bfloat16* c_ln2_b = sm + 12288, *c_ff2_b1 = sm + 12800, *c_ff2_b2 = sm + 14848;
  __hip_bfloat16* c_lnf_g = sm + 15360, *c_lnf_b = sm + 15872;

  // --- input normalization (f32 world) ---
  {
    WPack wp;
    wp.s[0] = {(const float*)d_in[3],  0,      131072};  // ff1_w1
    wp.s[1] = {(const float*)d_in[5],  131072, 131072};  // ff1_w2
    wp.s[2] = {(const float*)d_in[9],  262144, 98304};   // qkv_w
    wp.s[3] = {(const float*)d_in[11], 360448, 32768};   // out_w
    wp.s[4] = {(const float*)d_in[15], 393216, 65536};   // pw1_w
    wp.s[5] = {(const float*)d_in[23], 458752, 32768};   // pw2_w
    wp.s[6] = {(const float*)d_in[27], 491520, 131072};  // ff2_w1
    wp.s[7] = {(const float*)d_in[29], 622592, 131072};  // ff2_w2
    cast_wall_kernel<<<2944, 256, 0, stream>>>(wp, wc);
  }
  cast_dww_kernel<<<1, 256, 0, stream>>>((const float*)d_in[17], wc_dwT);
  PtrPack pk;
  const int small_idx[23] = {1, 2, 4, 6, 7, 8, 10, 12, 13, 14, 16, 18,
                             19, 20, 21, 22, 24, 25, 26, 28, 30, 31, 32};
  for (int t = 0; t < 23; ++t) pk.p[t] = d_in[small_idx[t]];
  cast_small_kernel<<<1, 256, 0, stream>>>(pk, sm);

  // --- FF1 (half-scale): xsb = 1.5*x + 0.5*(silu(ln(x)@w1)@w2 + b2) ---
  ln_kernel<<<2048, 256, 0, stream>>>(x, c_ln1_g, c_ln1_b, t0);
  gemm_bt<1><<<dim3(64, 16), 256, 0, stream>>>(t0, wc_ff1_w1, c_ff1_b1, t1, nullptr, 512, 2048);
  gemm64_resid<1><<<dim3(128, 4), 256, 0, stream>>>(t1, wc_ff1_w2, c_ff1_b2, x, xsb, 2048, 1.5f, 0.5f);

  // --- Attention (qkv GEMM with fused V-transpose; MFMA flash v6) ---
  lnb_kernel<<<2048, 256, 0, stream>>>(xsb, c_lna_g, c_lna_b, t0);
  gemm_bt<3><<<dim3(64, 12), 256, 0, stream>>>(t0, wc_qkv_w, c_qkv_b, t1, vT, 512, 1536);
  attn_kernel<<<512, 256, 0, stream>>>(t1, vT, t2);
  gemm64_resid<0><<<dim3(128, 4), 256, 0, stream>>>(t2, wc_out_w, c_out_b, xsb, xsb, 512, 1.0f, 1.0f);

  // --- Conv module ---
  lnb_kernel<<<2048, 256, 0, stream>>>(xsb, c_lnc_g, c_lnc_b, t0);
  gemm_bt<0><<<dim3(64, 8), 256, 0, stream>>>(t0, wc_pw1_w, c_pw1_b, t1, nullptr, 512, 1024);
  glu8_kernel<<<2048, 256, 0, stream>>>(t1, t2);
  dwconv8_kernel<<<2048, 256, 0, stream>>>(t2, wc_dwT, c_dw_b, c_bn_g, c_bn_b, c_bn_m, c_bn_v, t0);
  gemm64_resid<0><<<dim3(128, 4), 256, 0, stream>>>(t0, wc_pw2_w, c_pw2_b, xsb, xsb, 512, 2.0f, 1.0f);

  // --- FF2 (half-scale) ---
  lnb_kernel<<<2048, 256, 0, stream>>>(xsb, c_ln2_g, c_ln2_b, t0);
  gemm_bt<1><<<dim3(64, 16), 256, 0, stream>>>(t0, wc_ff2_w1, c_ff2_b1, t1, nullptr, 512, 2048);
  gemm64_resid<0><<<dim3(128, 4), 256, 0, stream>>>(t1, wc_ff2_w2, c_ff2_b2, xsb, xsb, 2048, 1.5f, 0.5f);

  // --- Final LN -> FP32 out ---
  lnf_kernel<<<2048, 256, 0, stream>>>(xsb, c_lnf_g, c_lnf_b, out);
}

// Round 20
// 288.514 us; speedup vs baseline: 1.0755x; 1.0253x over previous
//
#include <hip/hip_runtime.h>
#include <hip/hip_bf16.h>

typedef __attribute__((ext_vector_type(8))) short bf16x8;
typedef __attribute__((ext_vector_type(4))) short bf16x4;
typedef __attribute__((ext_vector_type(4))) float f32x4;

#define NTOK 8192
#define SEQ  1024
#define NH   8

__device__ __forceinline__ float bfs2f(short s) {
  union { unsigned u; float f; } x; x.u = ((unsigned)(unsigned short)s) << 16; return x.f;
}
__device__ __forceinline__ short f2bfs(float f) {
  __hip_bfloat16 h = __float2bfloat16(f);
  return *reinterpret_cast<short*>(&h);
}
__device__ __forceinline__ float bfp2f(const __hip_bfloat16* p) {
  return bfs2f(*reinterpret_cast<const short*>(p));
}

__device__ __forceinline__ void gld16(const void* g, void* l) {
  __builtin_amdgcn_global_load_lds(
      (__attribute__((address_space(1))) void*)const_cast<void*>(g),
      (__attribute__((address_space(3))) void*)l, 16, 0, 0);
}

// ---------------- fused f32 weight -> bf16 cast (all big tensors, 1 launch) ------
struct WSeg { const float* src; unsigned dst_off; unsigned nvec; };
struct WPack { WSeg s[8]; };

__global__ __launch_bounds__(256) void cast_wall_kernel(WPack p,
                                                        __hip_bfloat16* __restrict__ dst) {
  unsigned v = blockIdx.x * 256 + threadIdx.x;
#pragma unroll
  for (int t = 0; t < 8; ++t) {
    if (v < p.s[t].nvec) {
      const float* s = p.s[t].src + (size_t)v * 8;
      f32x4 a = *reinterpret_cast<const f32x4*>(s);
      f32x4 b = *reinterpret_cast<const f32x4*>(s + 4);
      bf16x8 o;
#pragma unroll
      for (int j = 0; j < 4; ++j) { o[j] = f2bfs(a[j]); o[4 + j] = f2bfs(b[j]); }
      *reinterpret_cast<bf16x8*>(reinterpret_cast<short*>(dst) +
                                 (size_t)(p.s[t].dst_off + v) * 8) = o;
      return;
    }
    v -= p.s[t].nvec;
  }
}

// ---------------- dw_w f32 [512][31] -> bf16 transposed [31][512] ----------------
__global__ __launch_bounds__(256) void cast_dww_kernel(const float* __restrict__ src,
                                                       __hip_bfloat16* __restrict__ dst) {
  for (int k = 0; k < 31; ++k)
    for (int c = threadIdx.x; c < 512; c += 256)
      dst[k * 512 + c] = __float2bfloat16(src[c * 31 + k]);
}

struct PtrPack { const void* p[23]; };

__global__ __launch_bounds__(256) void cast_small_kernel(PtrPack pk,
                                                         __hip_bfloat16* __restrict__ dst) {
  constexpr int sizes[23] = {512, 512, 2048, 512, 512, 512, 1536, 512, 512, 512, 1024, 512,
                             512, 512, 512, 512, 512, 512, 512, 2048, 512, 512, 512};
  int off = 0;
  for (int t = 0; t < 23; ++t) {
    const int n = sizes[t];
    for (int i = threadIdx.x; i < n; i += 256)
      dst[off + i] = __float2bfloat16(((const float*)pk.p[t])[i]);
    off += n;
  }
}

__global__ void ws_bad_kernel(float* __restrict__ out) {
  if (threadIdx.x == 0) out[0] = 5000.f;
}

// ---------------- LayerNorm: bf16 stream in -> bf16 out (D=512) ----------------
__global__ __launch_bounds__(256) void lnb_kernel(const __hip_bfloat16* __restrict__ in,
                                                  const __hip_bfloat16* __restrict__ g,
                                                  const __hip_bfloat16* __restrict__ b,
                                                  __hip_bfloat16* __restrict__ out) {
  const int wv = threadIdx.x >> 6, ln = threadIdx.x & 63;
  const int row = blockIdx.x * 4 + wv;
  bf16x8 iv = *reinterpret_cast<const bf16x8*>(in + (size_t)row * 512 + ln * 8);
  float v[8];
#pragma unroll
  for (int j = 0; j < 8; ++j) v[j] = bfs2f(iv[j]);
  float s = 0.f;
#pragma unroll
  for (int j = 0; j < 8; ++j) s += v[j];
  for (int m = 1; m < 64; m <<= 1) s += __shfl_xor(s, m);
  const float mean = s * (1.f / 512.f);
  float q = 0.f;
#pragma unroll
  for (int j = 0; j < 8; ++j) { float d = v[j] - mean; q += d * d; }
  for (int m = 1; m < 64; m <<= 1) q += __shfl_xor(q, m);
  const float rstd = rsqrtf(q * (1.f / 512.f) + 1e-5f);
  bf16x8 gg = *reinterpret_cast<const bf16x8*>(g + ln * 8);
  bf16x8 bb = *reinterpret_cast<const bf16x8*>(b + ln * 8);
  bf16x8 ov;
#pragma unroll
  for (int j = 0; j < 8; ++j)
    ov[j] = f2bfs((v[j] - mean) * rstd * bfs2f(gg[j]) + bfs2f(bb[j]));
  *reinterpret_cast<bf16x8*>(out + (size_t)row * 512 + ln * 8) = ov;
}

// ---------------- LayerNorm: fp32 in -> bf16 out (first LN reads x) --------------
__global__ __launch_bounds__(256) void ln_kernel(const float* __restrict__ in,
                                                 const __hip_bfloat16* __restrict__ g,
                                                 const __hip_bfloat16* __restrict__ b,
                                                 __hip_bfloat16* __restrict__ out) {
  const int wv = threadIdx.x >> 6, ln = threadIdx.x & 63;
  const int row = blockIdx.x * 4 + wv;
  const float* p = in + (size_t)row * 512 + ln * 8;
  float v[8];
  {
    const f32x4* p4 = reinterpret_cast<const f32x4*>(p);
    f32x4 a = p4[0], c = p4[1];
#pragma unroll
    for (int j = 0; j < 4; ++j) { v[j] = a[j]; v[4 + j] = c[j]; }
  }
  float s = 0.f;
#pragma unroll
  for (int j = 0; j < 8; ++j) s += v[j];
  for (int m = 1; m < 64; m <<= 1) s += __shfl_xor(s, m);
  const float mean = s * (1.f / 512.f);
  float q = 0.f;
#pragma unroll
  for (int j = 0; j < 8; ++j) { float d = v[j] - mean; q += d * d; }
  for (int m = 1; m < 64; m <<= 1) q += __shfl_xor(q, m);
  const float rstd = rsqrtf(q * (1.f / 512.f) + 1e-5f);
  bf16x8 gg = *reinterpret_cast<const bf16x8*>(g + ln * 8);
  bf16x8 bb = *reinterpret_cast<const bf16x8*>(b + ln * 8);
  bf16x8 ov;
#pragma unroll
  for (int j = 0; j < 8; ++j)
    ov[j] = f2bfs((v[j] - mean) * rstd * bfs2f(gg[j]) + bfs2f(bb[j]));
  *reinterpret_cast<bf16x8*>(out + (size_t)row * 512 + ln * 8) = ov;
}

// ---------------- final LayerNorm: bf16 stream in -> FP32 out --------------------
__global__ __launch_bounds__(256) void lnf_kernel(const __hip_bfloat16* __restrict__ in,
                                                  const __hip_bfloat16* __restrict__ g,
                                                  const __hip_bfloat16* __restrict__ b,
                                                  float* __restrict__ out) {
  const int wv = threadIdx.x >> 6, ln = threadIdx.x & 63;
  const int row = blockIdx.x * 4 + wv;
  bf16x8 iv = *reinterpret_cast<const bf16x8*>(in + (size_t)row * 512 + ln * 8);
  float v[8];
#pragma unroll
  for (int j = 0; j < 8; ++j) v[j] = bfs2f(iv[j]);
  float s = 0.f;
#pragma unroll
  for (int j = 0; j < 8; ++j) s += v[j];
  for (int m = 1; m < 64; m <<= 1) s += __shfl_xor(s, m);
  const float mean = s * (1.f / 512.f);
  float q = 0.f;
#pragma unroll
  for (int j = 0; j < 8; ++j) { float d = v[j] - mean; q += d * d; }
  for (int m = 1; m < 64; m <<= 1) q += __shfl_xor(q, m);
  const float rstd = rsqrtf(q * (1.f / 512.f) + 1e-5f);
  bf16x8 gg = *reinterpret_cast<const bf16x8*>(g + ln * 8);
  bf16x8 bb = *reinterpret_cast<const bf16x8*>(b + ln * 8);
  f32x4 o0, o1;
#pragma unroll
  for (int j = 0; j < 4; ++j) {
    o0[j] = (v[j] - mean) * rstd * bfs2f(gg[j]) + bfs2f(bb[j]);
    o1[j] = (v[4 + j] - mean) * rstd * bfs2f(gg[4 + j]) + bfs2f(bb[4 + j]);
  }
  float* op = out + (size_t)row * 512 + ln * 8;
  *reinterpret_cast<f32x4*>(op) = o0;
  *reinterpret_cast<f32x4*>(op + 4) = o1;
}

// ---------------- MFMA GEMM (m97 + T2 swizzle, XCD-swizzled, 3 blocks/CU) --------
// EPI 0: bf16 out ; EPI 1: bf16 silu ;
// EPI 3: qkv — Q/K to outb, V written TRANSPOSED to vTout[b,h,d,s] (short4).
template <int EPI>
__global__ __launch_bounds__(256, 3) void gemm_bt(const __hip_bfloat16* __restrict__ A,
                                                  const __hip_bfloat16* __restrict__ W,
                                                  const __hip_bfloat16* __restrict__ bias,
                                                  __hip_bfloat16* __restrict__ outb,
                                                  __hip_bfloat16* __restrict__ vTout,
                                                  int K, int M) {
  __shared__ __align__(16) __hip_bfloat16 As[128 * 64];
  __shared__ __align__(16) __hip_bfloat16 Bs[128 * 64];
  const int tid = threadIdx.x;
  const int wv = tid >> 6, ln = tid & 63;
  const int hi = ln >> 4, lo = ln & 15;
  const int lo7 = lo & 7;
  const int gx = gridDim.x;
  const int nwg = gx * gridDim.y;
  const int t = blockIdx.y * gx + blockIdx.x;
  const int w = (t & 7) * (nwg >> 3) + (t >> 3);
  const int n0 = (w & (gx - 1)) * 128;
  const int m0 = (w / gx) * 128;
  const int wr = wv >> 1, wc = wv & 1;
  const int srow = ln >> 3;
  const int scolz = (((ln & 7) ^ srow) << 3);   // swizzled source granule

  f32x4 acc[4][4] = {};

  for (int k0 = 0; k0 < K; k0 += 64) {
    __syncthreads();
#pragma unroll
    for (int i = 0; i < 4; ++i) {
      const int grp = i * 4 + wv;
      const int row = grp * 8 + srow;
      gld16(A + (size_t)(n0 + row) * K + k0 + scolz, As + grp * 512);
      gld16(W + (size_t)(m0 + row) * K + k0 + scolz, Bs + grp * 512);
    }
    __syncthreads();
#pragma unroll
    for (int kk2 = 0; kk2 < 2; ++kk2) {
      const int g0 = ((kk2 * 4 + hi) ^ lo7) << 3;   // swizzled read granule
      bf16x8 af[4], bfr[4];
#pragma unroll
      for (int r = 0; r < 4; ++r)
        af[r] = *reinterpret_cast<const bf16x8*>(As + (wr * 64 + r * 16 + lo) * 64 + g0);
#pragma unroll
      for (int c = 0; c < 4; ++c)
        bfr[c] = *reinterpret_cast<const bf16x8*>(Bs + (wc * 64 + c * 16 + lo) * 64 + g0);
#pragma unroll
      for (int r = 0; r < 4; ++r)
#pragma unroll
        for (int c = 0; c < 4; ++c)
          acc[r][c] = __builtin_amdgcn_mfma_f32_16x16x32_bf16(af[r], bfr[c], acc[r][c], 0, 0, 0);
    }
  }

#pragma unroll
  for (int r = 0; r < 4; ++r) {
#pragma unroll
    for (int c = 0; c < 4; ++c) {
      const int m = m0 + wc * 64 + c * 16 + lo;
      const float bv = bfp2f(bias + m);
      const int nb = n0 + wr * 64 + r * 16 + hi * 4;
      if constexpr (EPI == 3) {
        if (m >= 1024) {  // V part -> transposed store
          const int hd = m - 1024;
          __hip_bfloat16* vp = vTout +
              ((size_t)((nb >> 10) * NH + (hd >> 6)) * 64 + (hd & 63)) * 1024 + (nb & 1023);
          bf16x4 vv;
#pragma unroll
          for (int j = 0; j < 4; ++j) vv[j] = f2bfs(acc[r][c][j] + bv);
          *reinterpret_cast<bf16x4*>(vp) = vv;
          continue;
        }
      }
#pragma unroll
      for (int j = 0; j < 4; ++j) {
        const int n = nb + j;
        float v = acc[r][c][j] + bv;
        if constexpr (EPI == 1) v = v / (1.f + __expf(-v));
        outb[(size_t)n * M + m] = __float2bfloat16(v);
      }
    }
  }
}

// ---------------- MFMA GEMM, M=512 resid: BM=64 x BN=128 + T2 swizzle ------------
// resid(bf16)[idx] = alpha*rsrc[idx] + beta*(A@W^T + bias); rsrc f32 (RF32) or bf16.
template <int RF32>
__global__ __launch_bounds__(256, 4) void gemm64_resid(const __hip_bfloat16* __restrict__ A,
                                                       const __hip_bfloat16* __restrict__ W,
                                                       const __hip_bfloat16* __restrict__ bias,
                                                       const void* __restrict__ rsrc,
                                                       __hip_bfloat16* __restrict__ resid,
                                                       int K, float alpha, float beta) {
  __shared__ __align__(16) __hip_bfloat16 As[64 * 64];
  __shared__ __align__(16) __hip_bfloat16 Bs[128 * 64];
  const int tid = threadIdx.x;
  const int wv = tid >> 6, ln = tid & 63;
  const int hi = ln >> 4, lo = ln & 15;
  const int lo7 = lo & 7;
  const int gx = gridDim.x;
  const int nwg = gx * gridDim.y;
  const int t = blockIdx.y * gx + blockIdx.x;
  const int w = (t & 7) * (nwg >> 3) + (t >> 3);
  const int n0 = (w & (gx - 1)) * 64;
  const int m0 = (w / gx) * 128;
  const int wr = wv >> 1, wc = wv & 1;
  const int srow = ln >> 3;
  const int scolz = (((ln & 7) ^ srow) << 3);

  f32x4 acc[2][4] = {};

  for (int k0 = 0; k0 < K; k0 += 64) {
    __syncthreads();
#pragma unroll
    for (int i = 0; i < 2; ++i) {
      const int grp = i * 4 + wv;
      gld16(A + (size_t)(n0 + grp * 8 + srow) * K + k0 + scolz, As + grp * 512);
    }
#pragma unroll
    for (int i = 0; i < 4; ++i) {
      const int grp = i * 4 + wv;
      gld16(W + (size_t)(m0 + grp * 8 + srow) * K + k0 + scolz, Bs + grp * 512);
    }
    __syncthreads();
#pragma unroll
    for (int kk2 = 0; kk2 < 2; ++kk2) {
      const int g0 = ((kk2 * 4 + hi) ^ lo7) << 3;
      bf16x8 af[2], bfr[4];
#pragma unroll
      for (int r = 0; r < 2; ++r)
        af[r] = *reinterpret_cast<const bf16x8*>(As + (wr * 32 + r * 16 + lo) * 64 + g0);
#pragma unroll
      for (int c = 0; c < 4; ++c)
        bfr[c] = *reinterpret_cast<const bf16x8*>(Bs + (wc * 64 + c * 16 + lo) * 64 + g0);
#pragma unroll
      for (int r = 0; r < 2; ++r)
#pragma unroll
        for (int c = 0; c < 4; ++c)
          acc[r][c] = __builtin_amdgcn_mfma_f32_16x16x32_bf16(af[r], bfr[c], acc[r][c], 0, 0, 0);
    }
  }

#pragma unroll
  for (int r = 0; r < 2; ++r) {
#pragma unroll
    for (int c = 0; c < 4; ++c) {
      const int m = m0 + wc * 64 + c * 16 + lo;
      const float bv = bfp2f(bias + m);
#pragma unroll
      for (int j = 0; j < 4; ++j) {
        const int n = n0 + wr * 32 + r * 16 + hi * 4 + j;
        const size_t idx = (size_t)n * 512 + m;
        const float rv = RF32 ? ((const float*)rsrc)[idx]
                              : bfs2f(((const short*)rsrc)[idx]);
        resid[idx] = __float2bfloat16(alpha * rv + beta * (acc[r][c][j] + bv));
      }
    }
  }
}

// ---------------- pw1 GEMM with FUSED GLU: out[n,m] = a*sigmoid(gate) ------------
// a    = A @ W[m]^T      + bias[m]        (m in 0..511)
// gate = A @ W[m+512]^T  + bias[m+512]
// BM=64, BN=128 output cols; block stages BOTH W panels over the shared A tile.
// Eliminates the separate glu kernel and the 16 MB t1 round trip.
__global__ __launch_bounds__(256, 3) void gemm_glu(const __hip_bfloat16* __restrict__ A,
                                                   const __hip_bfloat16* __restrict__ W,
                                                   const __hip_bfloat16* __restrict__ bias,
                                                   __hip_bfloat16* __restrict__ outb,
                                                   int K) {
  __shared__ __align__(16) __hip_bfloat16 As[64 * 64];
  __shared__ __align__(16) __hip_bfloat16 Ba[128 * 64];
  __shared__ __align__(16) __hip_bfloat16 Bg[128 * 64];
  const int tid = threadIdx.x;
  const int wv = tid >> 6, ln = tid & 63;
  const int hi = ln >> 4, lo = ln & 15;
  const int lo7 = lo & 7;
  const int gx = gridDim.x;                    // 128
  const int nwg = gx * gridDim.y;              // 512
  const int t = blockIdx.y * gx + blockIdx.x;
  const int w = (t & 7) * (nwg >> 3) + (t >> 3);
  const int n0 = (w & (gx - 1)) * 64;
  const int m0 = (w / gx) * 128;               // output col block (0..383 step 128)
  const int wr = wv >> 1, wc = wv & 1;
  const int srow = ln >> 3;
  const int scolz = (((ln & 7) ^ srow) << 3);

  f32x4 acca[2][4] = {}, accg[2][4] = {};

  for (int k0 = 0; k0 < K; k0 += 64) {
    __syncthreads();
#pragma unroll
    for (int i = 0; i < 2; ++i) {
      const int grp = i * 4 + wv;
      gld16(A + (size_t)(n0 + grp * 8 + srow) * K + k0 + scolz, As + grp * 512);
    }
#pragma unroll
    for (int i = 0; i < 4; ++i) {
      const int grp = i * 4 + wv;
      gld16(W + (size_t)(m0 + grp * 8 + srow) * K + k0 + scolz, Ba + grp * 512);
      gld16(W + (size_t)(512 + m0 + grp * 8 + srow) * K + k0 + scolz, Bg + grp * 512);
    }
    __syncthreads();
#pragma unroll
    for (int kk2 = 0; kk2 < 2; ++kk2) {
      const int g0 = ((kk2 * 4 + hi) ^ lo7) << 3;
      bf16x8 af[2], ba[4], bg[4];
#pragma unroll
      for (int r = 0; r < 2; ++r)
        af[r] = *reinterpret_cast<const bf16x8*>(As + (wr * 32 + r * 16 + lo) * 64 + g0);
#pragma unroll
      for (int c = 0; c < 4; ++c) {
        ba[c] = *reinterpret_cast<const bf16x8*>(Ba + (wc * 64 + c * 16 + lo) * 64 + g0);
        bg[c] = *reinterpret_cast<const bf16x8*>(Bg + (wc * 64 + c * 16 + lo) * 64 + g0);
      }
#pragma unroll
      for (int r = 0; r < 2; ++r)
#pragma unroll
        for (int c = 0; c < 4; ++c) {
          acca[r][c] = __builtin_amdgcn_mfma_f32_16x16x32_bf16(af[r], ba[c], acca[r][c], 0, 0, 0);
          accg[r][c] = __builtin_amdgcn_mfma_f32_16x16x32_bf16(af[r], bg[c], accg[r][c], 0, 0, 0);
        }
    }
  }

#pragma unroll
  for (int r = 0; r < 2; ++r) {
#pragma unroll
    for (int c = 0; c < 4; ++c) {
      const int m = m0 + wc * 64 + c * 16 + lo;
      const float bva = bfp2f(bias + m);
      const float bvg = bfp2f(bias + 512 + m);
#pragma unroll
      for (int j = 0; j < 4; ++j) {
        const int n = n0 + wr * 32 + r * 16 + hi * 4 + j;
        const float a = acca[r][c][j] + bva;
        const float g = accg[r][c][j] + bvg;
        outb[(size_t)n * 512 + m] = __float2bfloat16(a / (1.f + __expf(-g)));
      }
    }
  }
}

// ---------------- MFMA flash attention v6: 2 q-tiles/wave, K/V frag reuse --------
__global__ __launch_bounds__(256, 2) void attn_kernel(const __hip_bfloat16* __restrict__ qkv,
                                                      const __hip_bfloat16* __restrict__ vT,
                                                      __hip_bfloat16* __restrict__ ctx) {
  __shared__ __align__(16) short Ks[2][64 * 64];
  __shared__ __align__(16) short Vs[2][64 * 64];
  __shared__ __align__(16) short P[4][16][64];
  const int tid = threadIdx.x;
  const int wv = tid >> 6, ln = tid & 63;
  const int hi = ln >> 4, lo = ln & 15;
  const int lo7 = lo & 7;
  const int blk = ((blockIdx.x & 7) << 6) | (blockIdx.x >> 3);
  const int qt = blk & 7, h = (blk >> 3) & 7, b = blk >> 6;
  const int q0 = qt * 128 + wv * 16;   // tile A rows; tile B = q0 + 64

  const int srow8 = ln >> 3;
  const int gsrc = (ln & 7) ^ srow8;

  bf16x8 aq0a, aq1a, aq0b, aq1b;
  {
    const __hip_bfloat16* qpa = qkv + (size_t)(b * SEQ + q0 + lo) * 1536 + h * 64 + hi * 8;
    const __hip_bfloat16* qpb = qpa + (size_t)64 * 1536;
    bf16x8 r0 = *reinterpret_cast<const bf16x8*>(qpa);
    bf16x8 r1 = *reinterpret_cast<const bf16x8*>(qpa + 32);
    bf16x8 r2 = *reinterpret_cast<const bf16x8*>(qpb);
    bf16x8 r3 = *reinterpret_cast<const bf16x8*>(qpb + 32);
#pragma unroll
    for (int j = 0; j < 8; ++j) {
      aq0a[j] = f2bfs(bfs2f(r0[j]) * 0.125f);
      aq1a[j] = f2bfs(bfs2f(r1[j]) * 0.125f);
      aq0b[j] = f2bfs(bfs2f(r2[j]) * 0.125f);
      aq1b[j] = f2bfs(bfs2f(r3[j]) * 0.125f);
    }
  }

  const __hip_bfloat16* kbase = qkv + 512 + h * 64 + (size_t)b * SEQ * 1536;
  const __hip_bfloat16* vbase = vT + (size_t)(b * NH + h) * 64 * 1024;

  f32x4 oaccA[4] = {}, oaccB[4] = {};
  float lrowA[4] = {0.f, 0.f, 0.f, 0.f};
  float lrowB[4] = {0.f, 0.f, 0.f, 0.f};

#pragma unroll
  for (int c = 0; c < 2; ++c) {
    const int r = c * 32 + wv * 8 + srow8;
    gld16(kbase + (size_t)r * 1536 + gsrc * 8, &Ks[0][(c * 32 + wv * 8) * 64]);
    gld16(vbase + (size_t)r * 1024 + gsrc * 8, &Vs[0][(c * 32 + wv * 8) * 64]);
  }
  __syncthreads();

  int cb = 0;
  for (int kt = 0; kt < 16; ++kt) {
    if (kt < 15) {
      const int kb2 = (kt + 1) * 64;
#pragma unroll
      for (int c = 0; c < 2; ++c) {
        const int r = c * 32 + wv * 8 + srow8;
        gld16(kbase + (size_t)(kb2 + r) * 1536 + gsrc * 8,
              &Ks[cb ^ 1][(c * 32 + wv * 8) * 64]);
        gld16(vbase + (size_t)r * 1024 + kb2 + gsrc * 8,
              &Vs[cb ^ 1][(c * 32 + wv * 8) * 64]);
      }
    }

    bf16x8 bk0[4], bk1[4];
#pragma unroll
    for (int nt = 0; nt < 4; ++nt) {
      const short* kr = &Ks[cb][(nt * 16 + lo) * 64];
      bk0[nt] = *reinterpret_cast<const bf16x8*>(kr + ((hi ^ lo7) << 3));
      bk1[nt] = *reinterpret_cast<const bf16x8*>(kr + (((hi + 4) ^ lo7) << 3));
    }
    f32x4 scA[4] = {}, scB[4] = {};
#pragma unroll
    for (int nt = 0; nt < 4; ++nt) {
      scA[nt] = __builtin_amdgcn_mfma_f32_16x16x32_bf16(aq0a, bk0[nt], scA[nt], 0, 0, 0);
      scA[nt] = __builtin_amdgcn_mfma_f32_16x16x32_bf16(aq1a, bk1[nt], scA[nt], 0, 0, 0);
      scB[nt] = __builtin_amdgcn_mfma_f32_16x16x32_bf16(aq0b, bk0[nt], scB[nt], 0, 0, 0);
      scB[nt] = __builtin_amdgcn_mfma_f32_16x16x32_bf16(aq1b, bk1[nt], scB[nt], 0, 0, 0);
    }

    bf16x8 bv0[4], bv1[4];
#pragma unroll
    for (int dt = 0; dt < 4; ++dt) {
      const short* vr = &Vs[cb][(dt * 16 + lo) * 64];
      bv0[dt] = *reinterpret_cast<const bf16x8*>(vr + ((hi ^ lo7) << 3));
      bv1[dt] = *reinterpret_cast<const bf16x8*>(vr + (((hi + 4) ^ lo7) << 3));
    }

#pragma unroll
    for (int j = 0; j < 4; ++j) {
      const int prow = hi * 4 + j;
      const int pswz = (prow & 7) << 3;
#pragma unroll
      for (int nt = 0; nt < 4; ++nt) {
        const float p = __expf(scA[nt][j]);
        P[wv][prow][(nt * 16 + lo) ^ pswz] = f2bfs(p);
        lrowA[j] += p;
      }
    }
    asm volatile("" ::: "memory");
    {
      const short* pr = &P[wv][lo][0];
      bf16x8 ap0 = *reinterpret_cast<const bf16x8*>(pr + ((hi ^ lo7) << 3));
      bf16x8 ap1 = *reinterpret_cast<const bf16x8*>(pr + (((hi + 4) ^ lo7) << 3));
#pragma unroll
      for (int dt = 0; dt < 4; ++dt) {
        oaccA[dt] = __builtin_amdgcn_mfma_f32_16x16x32_bf16(ap0, bv0[dt], oaccA[dt], 0, 0, 0);
        oaccA[dt] = __builtin_amdgcn_mfma_f32_16x16x32_bf16(ap1, bv1[dt], oaccA[dt], 0, 0, 0);
      }
    }
    asm volatile("" ::: "memory");

#pragma unroll
    for (int j = 0; j < 4; ++j) {
      const int prow = hi * 4 + j;
      const int pswz = (prow & 7) << 3;
#pragma unroll
      for (int nt = 0; nt < 4; ++nt) {
        const float p = __expf(scB[nt][j]);
        P[wv][prow][(nt * 16 + lo) ^ pswz] = f2bfs(p);
        lrowB[j] += p;
      }
    }
    asm volatile("" ::: "memory");
    {
      const short* pr = &P[wv][lo][0];
      bf16x8 ap0 = *reinterpret_cast<const bf16x8*>(pr + ((hi ^ lo7) << 3));
      bf16x8 ap1 = *reinterpret_cast<const bf16x8*>(pr + (((hi + 4) ^ lo7) << 3));
#pragma unroll
      for (int dt = 0; dt < 4; ++dt) {
        oaccB[dt] = __builtin_amdgcn_mfma_f32_16x16x32_bf16(ap0, bv0[dt], oaccB[dt], 0, 0, 0);
        oaccB[dt] = __builtin_amdgcn_mfma_f32_16x16x32_bf16(ap1, bv1[dt], oaccB[dt], 0, 0, 0);
      }
    }
    __syncthreads();
    cb ^= 1;
  }

#pragma unroll
  for (int j = 0; j < 4; ++j) {
    float sa = lrowA[j], sb = lrowB[j];
    sa += __shfl_xor(sa, 1); sb += __shfl_xor(sb, 1);
    sa += __shfl_xor(sa, 2); sb += __shfl_xor(sb, 2);
    sa += __shfl_xor(sa, 4); sb += __shfl_xor(sb, 4);
    sa += __shfl_xor(sa, 8); sb += __shfl_xor(sb, 8);
    lrowA[j] = sa; lrowB[j] = sb;
  }

#pragma unroll
  for (int dt = 0; dt < 4; ++dt)
#pragma unroll
    for (int j = 0; j < 4; ++j) {
      const int d = h * 64 + dt * 16 + lo;
      const int na = b * SEQ + q0 + hi * 4 + j;
      ctx[(size_t)na * 512 + d] = __float2bfloat16(oaccA[dt][j] / lrowA[j]);
      const int nb = na + 64;
      ctx[(size_t)nb * 512 + d] = __float2bfloat16(oaccB[dt][j] / lrowB[j]);
    }
}

// ---------------- depthwise conv K=31 + BN + SiLU, bf16 in, 8 ch/thread ----------
__global__ __launch_bounds__(256) void dwconv8_kernel(const __hip_bfloat16* __restrict__ cin,
                                                      const __hip_bfloat16* __restrict__ wkT,
                                                      const __hip_bfloat16* __restrict__ cb,
                                                      const __hip_bfloat16* __restrict__ bng,
                                                      const __hip_bfloat16* __restrict__ bnb,
                                                      const __hip_bfloat16* __restrict__ bnm,
                                                      const __hip_bfloat16* __restrict__ bnv,
                                                      __hip_bfloat16* __restrict__ outp) {
  const int i = blockIdx.x * 256 + threadIdx.x;
  const int c8 = i & 63;
  const int n = i >> 6;
  const int t = n & 1023;
  const int base = n - t;
  const int co = c8 * 8;

  float acc[8];
  {
    bf16x8 bv = *reinterpret_cast<const bf16x8*>(cb + co);
#pragma unroll
    for (int j = 0; j < 8; ++j) acc[j] = bfs2f(bv[j]);
  }
  const int k0 = (t >= 15) ? 0 : (15 - t);
  const int k1 = (t <= SEQ - 16) ? 31 : (SEQ - 1 - t + 16);
  const short* cin_s = reinterpret_cast<const short*>(cin);
  const short* wk_s = reinterpret_cast<const short*>(wkT);
  for (int k = k0; k < k1; ++k) {
    const int ts = t + k - 15;
    bf16x8 xv = *reinterpret_cast<const bf16x8*>(cin_s + (((size_t)(base + ts)) << 9) + co);
    bf16x8 wv = *reinterpret_cast<const bf16x8*>(wk_s + k * 512 + co);
#pragma unroll
    for (int j = 0; j < 8; ++j) acc[j] += bfs2f(xv[j]) * bfs2f(wv[j]);
  }
  bf16x8 g = *reinterpret_cast<const bf16x8*>(bng + co);
  bf16x8 bb = *reinterpret_cast<const bf16x8*>(bnb + co);
  bf16x8 bm = *reinterpret_cast<const bf16x8*>(bnm + co);
  bf16x8 bvv = *reinterpret_cast<const bf16x8*>(bnv + co);
  bf16x8 ov;
#pragma unroll
  for (int j = 0; j < 8; ++j) {
    const float scl = bfs2f(g[j]) * rsqrtf(bfs2f(bvv[j]) + 1e-5f);
    float v = (acc[j] - bfs2f(bm[j])) * scl + bfs2f(bb[j]);
    v = v / (1.f + __expf(-v));
    ov[j] = f2bfs(v);
  }
  *reinterpret_cast<bf16x8*>(reinterpret_cast<short*>(outp) + ((size_t)n << 9) + co) = ov;
}

extern "C" void kernel_launch(void* const* d_in, const int* in_sizes, int n_in,
                              void* d_out, int out_size, void* d_ws, size_t ws_size,
                              hipStream_t stream) {
  float* out = (float*)d_out;  // confirmed: f32 in / f32 out
  if (ws_size < ((size_t)80 << 20)) {
    ws_bad_kernel<<<1, 64, 0, stream>>>(out);  // sentinel 5000
    return;
  }

  const float* x = (const float*)d_in[0];

  char* ws = (char*)d_ws;
  __hip_bfloat16* xsb = (__hip_bfloat16*)ws;                             // 0-8 MB bf16 stream
  __hip_bfloat16* t0 = (__hip_bfloat16*)(ws + ((size_t)16 << 20));       // 16-24 MB
  __hip_bfloat16* t1 = (__hip_bfloat16*)(ws + ((size_t)24 << 20));       // 24-48 MB
  __hip_bfloat16* t2 = (__hip_bfloat16*)(ws + ((size_t)56 << 20));       // 56-64 MB
  __hip_bfloat16* wc = (__hip_bfloat16*)(ws + ((size_t)64 << 20));       // 64-76 MB
  __hip_bfloat16* vT = t1 + (size_t)NTOK * 1536;                         // 48-56 MB

  __hip_bfloat16* wc_ff1_w1 = wc + 0;
  __hip_bfloat16* wc_ff1_w2 = wc + 1048576;
  __hip_bfloat16* wc_qkv_w  = wc + 2097152;
  __hip_bfloat16* wc_out_w  = wc + 2883584;
  __hip_bfloat16* wc_pw1_w  = wc + 3145728;
  __hip_bfloat16* wc_pw2_w  = wc + 3670016;
  __hip_bfloat16* wc_ff2_w1 = wc + 3932160;
  __hip_bfloat16* wc_ff2_w2 = wc + 4980736;
  __hip_bfloat16* wc_dwT    = wc + 6029312;      // [31][512] bf16 transposed
  __hip_bfloat16* sm        = wc + 6045184;
  __hip_bfloat16* c_ln1_g = sm + 0,     *c_ln1_b = sm + 512,   *c_ff1_b1 = sm + 1024;
  __hip_bfloat16* c_ff1_b2 = sm + 3072, *c_lna_g = sm + 3584,  *c_lna_b = sm + 4096;
  __hip_bfloat16* c_qkv_b = sm + 4608,  *c_out_b = sm + 6144,  *c_lnc_g = sm + 6656;
  __hip_bfloat16* c_lnc_b = sm + 7168,  *c_pw1_b = sm + 7680,  *c_dw_b = sm + 8704;
  __hip_bfloat16* c_bn_g = sm + 9216,   *c_bn_b = sm + 9728,   *c_bn_m = sm + 10240;
  __hip_bfloat16* c_bn_v = sm + 10752,  *c_pw2_b = sm + 11264, *c_ln2_g = sm + 11776;
  __hip_bfloat16* c_ln2_b = sm + 12288, *c_ff2_b1 = sm + 12800, *c_ff2_b2 = sm + 14848;
  __hip_bfloat16* c_lnf_g = sm + 15360, *c_lnf_b = sm + 15872;

  // --- input normalization (f32 world) ---
  {
    WPack wp;
    wp.s[0] = {(const float*)d_in[3],  0,      131072};  // ff1_w1
    wp.s[1] = {(const float*)d_in[5],  131072, 131072};  // ff1_w2
    wp.s[2] = {(const float*)d_in[9],  262144, 98304};   // qkv_w
    wp.s[3] = {(const float*)d_in[11], 360448, 32768};   // out_w
    wp.s[4] = {(const float*)d_in[15], 393216, 65536};   // pw1_w
    wp.s[5] = {(const float*)d_in[23], 458752, 32768};   // pw2_w
    wp.s[6] = {(const float*)d_in[27], 491520, 131072};  // ff2_w1
    wp.s[7] = {(const float*)d_in[29], 622592, 131072};  // ff2_w2
    cast_wall_kernel<<<2944, 256, 0, stream>>>(wp, wc);
  }
  cast_dww_kernel<<<1, 256, 0, stream>>>((const float*)d_in[17], wc_dwT);
  PtrPack pk;
  const int small_idx[23] = {1, 2, 4, 6, 7, 8, 10, 12, 13, 14, 16, 18,
                             19, 20, 21, 22, 24, 25, 26, 28, 30, 31, 32};
  for (int t = 0; t < 23; ++t) pk.p[t] = d_in[small_idx[t]];
  cast_small_kernel<<<1, 256, 0, stream>>>(pk, sm);

  // --- FF1 (half-scale): xsb = 1.5*x + 0.5*(silu(ln(x)@w1)@w2 + b2) ---
  ln_kernel<<<2048, 256, 0, stream>>>(x, c_ln1_g, c_ln1_b, t0);
  gemm_bt<1><<<dim3(64, 16), 256, 0, stream>>>(t0, wc_ff1_w1, c_ff1_b1, t1, nullptr, 512, 2048);
  gemm64_resid<1><<<dim3(128, 4), 256, 0, stream>>>(t1, wc_ff1_w2, c_ff1_b2, x, xsb, 2048, 1.5f, 0.5f);

  // --- Attention (qkv GEMM with fused V-transpose; MFMA flash v6) ---
  lnb_kernel<<<2048, 256, 0, stream>>>(xsb, c_lna_g, c_lna_b, t0);
  gemm_bt<3><<<dim3(64, 12), 256, 0, stream>>>(t0, wc_qkv_w, c_qkv_b, t1, vT, 512, 1536);
  attn_kernel<<<512, 256, 0, stream>>>(t1, vT, t2);
  gemm64_resid<0><<<dim3(128, 4), 256, 0, stream>>>(t2, wc_out_w, c_out_b, xsb, xsb, 512, 1.0f, 1.0f);

  // --- Conv module (pw1 GEMM with fused GLU) ---
  lnb_kernel<<<2048, 256, 0, stream>>>(xsb, c_lnc_g, c_lnc_b, t0);
  gemm_glu<<<dim3(128, 4), 256, 0, stream>>>(t0, wc_pw1_w, c_pw1_b, t2, 512);
  dwconv8_kernel<<<2048, 256, 0, stream>>>(t2, wc_dwT, c_dw_b, c_bn_g, c_bn_b, c_bn_m, c_bn_v, t0);
  gemm64_resid<0><<<dim3(128, 4), 256, 0, stream>>>(t0, wc_pw2_w, c_pw2_b, xsb, xsb, 512, 2.0f, 1.0f);

  // --- FF2 (half-scale) ---
  lnb_kernel<<<2048, 256, 0, stream>>>(xsb, c_ln2_g, c_ln2_b, t0);
  gemm_bt<1><<<dim3(64, 16), 256, 0, stream>>>(t0, wc_ff2_w1, c_ff2_b1, t1, nullptr, 512, 2048);
  gemm64_resid<0><<<dim3(128, 4), 256, 0, stream>>>(t1, wc_ff2_w2, c_ff2_b2, xsb, xsb, 2048, 1.5f, 0.5f);

  // --- Final LN -> FP32 out ---
  lnf_kernel<<<2048, 256, 0, stream>>>(xsb, c_lnf_g, c_lnf_b, out);
}

// Round 21
// 287.153 us; speedup vs baseline: 1.0806x; 1.0047x over previous
//
#include <hip/hip_runtime.h>
#include <hip/hip_bf16.h>

typedef __attribute__((ext_vector_type(8))) short bf16x8;
typedef __attribute__((ext_vector_type(4))) short bf16x4;
typedef __attribute__((ext_vector_type(4))) float f32x4;

#define NTOK 8192
#define SEQ  1024
#define NH   8

__device__ __forceinline__ float bfs2f(short s) {
  union { unsigned u; float f; } x; x.u = ((unsigned)(unsigned short)s) << 16; return x.f;
}
__device__ __forceinline__ short f2bfs(float f) {
  __hip_bfloat16 h = __float2bfloat16(f);
  return *reinterpret_cast<short*>(&h);
}
__device__ __forceinline__ float bfp2f(const __hip_bfloat16* p) {
  return bfs2f(*reinterpret_cast<const short*>(p));
}

__device__ __forceinline__ void gld16(const void* g, void* l) {
  __builtin_amdgcn_global_load_lds(
      (__attribute__((address_space(1))) void*)const_cast<void*>(g),
      (__attribute__((address_space(3))) void*)l, 16, 0, 0);
}

// ---------------- fused f32 weight -> bf16 cast (all big tensors, 1 launch) ------
struct WSeg { const float* src; unsigned dst_off; unsigned nvec; };
struct WPack { WSeg s[8]; };

__global__ __launch_bounds__(256) void cast_wall_kernel(WPack p,
                                                        __hip_bfloat16* __restrict__ dst) {
  unsigned v = blockIdx.x * 256 + threadIdx.x;
#pragma unroll
  for (int t = 0; t < 8; ++t) {
    if (v < p.s[t].nvec) {
      const float* s = p.s[t].src + (size_t)v * 8;
      f32x4 a = *reinterpret_cast<const f32x4*>(s);
      f32x4 b = *reinterpret_cast<const f32x4*>(s + 4);
      bf16x8 o;
#pragma unroll
      for (int j = 0; j < 4; ++j) { o[j] = f2bfs(a[j]); o[4 + j] = f2bfs(b[j]); }
      *reinterpret_cast<bf16x8*>(reinterpret_cast<short*>(dst) +
                                 (size_t)(p.s[t].dst_off + v) * 8) = o;
      return;
    }
    v -= p.s[t].nvec;
  }
}

// ---------------- dw_w f32 [512][31] -> bf16 transposed [31][512] ----------------
__global__ __launch_bounds__(256) void cast_dww_kernel(const float* __restrict__ src,
                                                       __hip_bfloat16* __restrict__ dst) {
  for (int k = 0; k < 31; ++k)
    for (int c = threadIdx.x; c < 512; c += 256)
      dst[k * 512 + c] = __float2bfloat16(src[c * 31 + k]);
}

struct PtrPack { const void* p[23]; };

__global__ __launch_bounds__(256) void cast_small_kernel(PtrPack pk,
                                                         __hip_bfloat16* __restrict__ dst) {
  constexpr int sizes[23] = {512, 512, 2048, 512, 512, 512, 1536, 512, 512, 512, 1024, 512,
                             512, 512, 512, 512, 512, 512, 512, 2048, 512, 512, 512};
  int off = 0;
  for (int t = 0; t < 23; ++t) {
    const int n = sizes[t];
    for (int i = threadIdx.x; i < n; i += 256)
      dst[off + i] = __float2bfloat16(((const float*)pk.p[t])[i]);
    off += n;
  }
}

__global__ void ws_bad_kernel(float* __restrict__ out) {
  if (threadIdx.x == 0) out[0] = 5000.f;
}

// ---------------- LayerNorm: bf16 stream in -> bf16 out (D=512) ----------------
__global__ __launch_bounds__(256) void lnb_kernel(const __hip_bfloat16* __restrict__ in,
                                                  const __hip_bfloat16* __restrict__ g,
                                                  const __hip_bfloat16* __restrict__ b,
                                                  __hip_bfloat16* __restrict__ out) {
  const int wv = threadIdx.x >> 6, ln = threadIdx.x & 63;
  const int row = blockIdx.x * 4 + wv;
  bf16x8 iv = *reinterpret_cast<const bf16x8*>(in + (size_t)row * 512 + ln * 8);
  float v[8];
#pragma unroll
  for (int j = 0; j < 8; ++j) v[j] = bfs2f(iv[j]);
  float s = 0.f;
#pragma unroll
  for (int j = 0; j < 8; ++j) s += v[j];
  for (int m = 1; m < 64; m <<= 1) s += __shfl_xor(s, m);
  const float mean = s * (1.f / 512.f);
  float q = 0.f;
#pragma unroll
  for (int j = 0; j < 8; ++j) { float d = v[j] - mean; q += d * d; }
  for (int m = 1; m < 64; m <<= 1) q += __shfl_xor(q, m);
  const float rstd = rsqrtf(q * (1.f / 512.f) + 1e-5f);
  bf16x8 gg = *reinterpret_cast<const bf16x8*>(g + ln * 8);
  bf16x8 bb = *reinterpret_cast<const bf16x8*>(b + ln * 8);
  bf16x8 ov;
#pragma unroll
  for (int j = 0; j < 8; ++j)
    ov[j] = f2bfs((v[j] - mean) * rstd * bfs2f(gg[j]) + bfs2f(bb[j]));
  *reinterpret_cast<bf16x8*>(out + (size_t)row * 512 + ln * 8) = ov;
}

// ---------------- LayerNorm: fp32 in -> bf16 out (first LN reads x) --------------
__global__ __launch_bounds__(256) void ln_kernel(const float* __restrict__ in,
                                                 const __hip_bfloat16* __restrict__ g,
                                                 const __hip_bfloat16* __restrict__ b,
                                                 __hip_bfloat16* __restrict__ out) {
  const int wv = threadIdx.x >> 6, ln = threadIdx.x & 63;
  const int row = blockIdx.x * 4 + wv;
  const float* p = in + (size_t)row * 512 + ln * 8;
  float v[8];
  {
    const f32x4* p4 = reinterpret_cast<const f32x4*>(p);
    f32x4 a = p4[0], c = p4[1];
#pragma unroll
    for (int j = 0; j < 4; ++j) { v[j] = a[j]; v[4 + j] = c[j]; }
  }
  float s = 0.f;
#pragma unroll
  for (int j = 0; j < 8; ++j) s += v[j];
  for (int m = 1; m < 64; m <<= 1) s += __shfl_xor(s, m);
  const float mean = s * (1.f / 512.f);
  float q = 0.f;
#pragma unroll
  for (int j = 0; j < 8; ++j) { float d = v[j] - mean; q += d * d; }
  for (int m = 1; m < 64; m <<= 1) q += __shfl_xor(q, m);
  const float rstd = rsqrtf(q * (1.f / 512.f) + 1e-5f);
  bf16x8 gg = *reinterpret_cast<const bf16x8*>(g + ln * 8);
  bf16x8 bb = *reinterpret_cast<const bf16x8*>(b + ln * 8);
  bf16x8 ov;
#pragma unroll
  for (int j = 0; j < 8; ++j)
    ov[j] = f2bfs((v[j] - mean) * rstd * bfs2f(gg[j]) + bfs2f(bb[j]));
  *reinterpret_cast<bf16x8*>(out + (size_t)row * 512 + ln * 8) = ov;
}

// ---------------- final LayerNorm: bf16 stream in -> FP32 out --------------------
__global__ __launch_bounds__(256) void lnf_kernel(const __hip_bfloat16* __restrict__ in,
                                                  const __hip_bfloat16* __restrict__ g,
                                                  const __hip_bfloat16* __restrict__ b,
                                                  float* __restrict__ out) {
  const int wv = threadIdx.x >> 6, ln = threadIdx.x & 63;
  const int row = blockIdx.x * 4 + wv;
  bf16x8 iv = *reinterpret_cast<const bf16x8*>(in + (size_t)row * 512 + ln * 8);
  float v[8];
#pragma unroll
  for (int j = 0; j < 8; ++j) v[j] = bfs2f(iv[j]);
  float s = 0.f;
#pragma unroll
  for (int j = 0; j < 8; ++j) s += v[j];
  for (int m = 1; m < 64; m <<= 1) s += __shfl_xor(s, m);
  const float mean = s * (1.f / 512.f);
  float q = 0.f;
#pragma unroll
  for (int j = 0; j < 8; ++j) { float d = v[j] - mean; q += d * d; }
  for (int m = 1; m < 64; m <<= 1) q += __shfl_xor(q, m);
  const float rstd = rsqrtf(q * (1.f / 512.f) + 1e-5f);
  bf16x8 gg = *reinterpret_cast<const bf16x8*>(g + ln * 8);
  bf16x8 bb = *reinterpret_cast<const bf16x8*>(b + ln * 8);
  f32x4 o0, o1;
#pragma unroll
  for (int j = 0; j < 4; ++j) {
    o0[j] = (v[j] - mean) * rstd * bfs2f(gg[j]) + bfs2f(bb[j]);
    o1[j] = (v[4 + j] - mean) * rstd * bfs2f(gg[4 + j]) + bfs2f(bb[4 + j]);
  }
  float* op = out + (size_t)row * 512 + ln * 8;
  *reinterpret_cast<f32x4*>(op) = o0;
  *reinterpret_cast<f32x4*>(op + 4) = o1;
}

// ---------------- MFMA GEMM (m97 + T2 swizzle, XCD-swizzled, 3 blocks/CU) --------
// EPI 0: bf16 out ; EPI 1: bf16 silu ;
// EPI 3: qkv — Q/K to outb, V written TRANSPOSED to vTout[b,h,d,s] (short4).
template <int EPI>
__global__ __launch_bounds__(256, 3) void gemm_bt(const __hip_bfloat16* __restrict__ A,
                                                  const __hip_bfloat16* __restrict__ W,
                                                  const __hip_bfloat16* __restrict__ bias,
                                                  __hip_bfloat16* __restrict__ outb,
                                                  __hip_bfloat16* __restrict__ vTout,
                                                  int K, int M) {
  __shared__ __align__(16) __hip_bfloat16 As[128 * 64];
  __shared__ __align__(16) __hip_bfloat16 Bs[128 * 64];
  const int tid = threadIdx.x;
  const int wv = tid >> 6, ln = tid & 63;
  const int hi = ln >> 4, lo = ln & 15;
  const int lo7 = lo & 7;
  const int gx = gridDim.x;
  const int nwg = gx * gridDim.y;
  const int t = blockIdx.y * gx + blockIdx.x;
  const int w = (t & 7) * (nwg >> 3) + (t >> 3);
  const int n0 = (w & (gx - 1)) * 128;
  const int m0 = (w / gx) * 128;
  const int wr = wv >> 1, wc = wv & 1;
  const int srow = ln >> 3;
  const int scolz = (((ln & 7) ^ srow) << 3);   // swizzled source granule

  f32x4 acc[4][4] = {};

  for (int k0 = 0; k0 < K; k0 += 64) {
    __syncthreads();
#pragma unroll
    for (int i = 0; i < 4; ++i) {
      const int grp = i * 4 + wv;
      const int row = grp * 8 + srow;
      gld16(A + (size_t)(n0 + row) * K + k0 + scolz, As + grp * 512);
      gld16(W + (size_t)(m0 + row) * K + k0 + scolz, Bs + grp * 512);
    }
    __syncthreads();
#pragma unroll
    for (int kk2 = 0; kk2 < 2; ++kk2) {
      const int g0 = ((kk2 * 4 + hi) ^ lo7) << 3;   // swizzled read granule
      bf16x8 af[4], bfr[4];
#pragma unroll
      for (int r = 0; r < 4; ++r)
        af[r] = *reinterpret_cast<const bf16x8*>(As + (wr * 64 + r * 16 + lo) * 64 + g0);
#pragma unroll
      for (int c = 0; c < 4; ++c)
        bfr[c] = *reinterpret_cast<const bf16x8*>(Bs + (wc * 64 + c * 16 + lo) * 64 + g0);
#pragma unroll
      for (int r = 0; r < 4; ++r)
#pragma unroll
        for (int c = 0; c < 4; ++c)
          acc[r][c] = __builtin_amdgcn_mfma_f32_16x16x32_bf16(af[r], bfr[c], acc[r][c], 0, 0, 0);
    }
  }

#pragma unroll
  for (int r = 0; r < 4; ++r) {
#pragma unroll
    for (int c = 0; c < 4; ++c) {
      const int m = m0 + wc * 64 + c * 16 + lo;
      const float bv = bfp2f(bias + m);
      const int nb = n0 + wr * 64 + r * 16 + hi * 4;
      if constexpr (EPI == 3) {
        if (m >= 1024) {  // V part -> transposed store
          const int hd = m - 1024;
          __hip_bfloat16* vp = vTout +
              ((size_t)((nb >> 10) * NH + (hd >> 6)) * 64 + (hd & 63)) * 1024 + (nb & 1023);
          bf16x4 vv;
#pragma unroll
          for (int j = 0; j < 4; ++j) vv[j] = f2bfs(acc[r][c][j] + bv);
          *reinterpret_cast<bf16x4*>(vp) = vv;
          continue;
        }
      }
#pragma unroll
      for (int j = 0; j < 4; ++j) {
        const int n = nb + j;
        float v = acc[r][c][j] + bv;
        if constexpr (EPI == 1) v = v / (1.f + __expf(-v));
        outb[(size_t)n * M + m] = __float2bfloat16(v);
      }
    }
  }
}

// ---------------- MFMA GEMM, M=512 resid: BM=64 x BN=128 + T2 swizzle ------------
// resid(bf16)[idx] = alpha*rsrc[idx] + beta*(A@W^T + bias); rsrc f32 (RF32) or bf16.
template <int RF32>
__global__ __launch_bounds__(256, 4) void gemm64_resid(const __hip_bfloat16* __restrict__ A,
                                                       const __hip_bfloat16* __restrict__ W,
                                                       const __hip_bfloat16* __restrict__ bias,
                                                       const void* __restrict__ rsrc,
                                                       __hip_bfloat16* __restrict__ resid,
                                                       int K, float alpha, float beta) {
  __shared__ __align__(16) __hip_bfloat16 As[64 * 64];
  __shared__ __align__(16) __hip_bfloat16 Bs[128 * 64];
  const int tid = threadIdx.x;
  const int wv = tid >> 6, ln = tid & 63;
  const int hi = ln >> 4, lo = ln & 15;
  const int lo7 = lo & 7;
  const int gx = gridDim.x;
  const int nwg = gx * gridDim.y;
  const int t = blockIdx.y * gx + blockIdx.x;
  const int w = (t & 7) * (nwg >> 3) + (t >> 3);
  const int n0 = (w & (gx - 1)) * 64;
  const int m0 = (w / gx) * 128;
  const int wr = wv >> 1, wc = wv & 1;
  const int srow = ln >> 3;
  const int scolz = (((ln & 7) ^ srow) << 3);

  f32x4 acc[2][4] = {};

  for (int k0 = 0; k0 < K; k0 += 64) {
    __syncthreads();
#pragma unroll
    for (int i = 0; i < 2; ++i) {
      const int grp = i * 4 + wv;
      gld16(A + (size_t)(n0 + grp * 8 + srow) * K + k0 + scolz, As + grp * 512);
    }
#pragma unroll
    for (int i = 0; i < 4; ++i) {
      const int grp = i * 4 + wv;
      gld16(W + (size_t)(m0 + grp * 8 + srow) * K + k0 + scolz, Bs + grp * 512);
    }
    __syncthreads();
#pragma unroll
    for (int kk2 = 0; kk2 < 2; ++kk2) {
      const int g0 = ((kk2 * 4 + hi) ^ lo7) << 3;
      bf16x8 af[2], bfr[4];
#pragma unroll
      for (int r = 0; r < 2; ++r)
        af[r] = *reinterpret_cast<const bf16x8*>(As + (wr * 32 + r * 16 + lo) * 64 + g0);
#pragma unroll
      for (int c = 0; c < 4; ++c)
        bfr[c] = *reinterpret_cast<const bf16x8*>(Bs + (wc * 64 + c * 16 + lo) * 64 + g0);
#pragma unroll
      for (int r = 0; r < 2; ++r)
#pragma unroll
        for (int c = 0; c < 4; ++c)
          acc[r][c] = __builtin_amdgcn_mfma_f32_16x16x32_bf16(af[r], bfr[c], acc[r][c], 0, 0, 0);
    }
  }

#pragma unroll
  for (int r = 0; r < 2; ++r) {
#pragma unroll
    for (int c = 0; c < 4; ++c) {
      const int m = m0 + wc * 64 + c * 16 + lo;
      const float bv = bfp2f(bias + m);
#pragma unroll
      for (int j = 0; j < 4; ++j) {
        const int n = n0 + wr * 32 + r * 16 + hi * 4 + j;
        const size_t idx = (size_t)n * 512 + m;
        const float rv = RF32 ? ((const float*)rsrc)[idx]
                              : bfs2f(((const short*)rsrc)[idx]);
        resid[idx] = __float2bfloat16(alpha * rv + beta * (acc[r][c][j] + bv));
      }
    }
  }
}

// ---------------- pw1 GEMM with FUSED GLU: out[n,m] = a*sigmoid(gate) ------------
__global__ __launch_bounds__(256, 3) void gemm_glu(const __hip_bfloat16* __restrict__ A,
                                                   const __hip_bfloat16* __restrict__ W,
                                                   const __hip_bfloat16* __restrict__ bias,
                                                   __hip_bfloat16* __restrict__ outb,
                                                   int K) {
  __shared__ __align__(16) __hip_bfloat16 As[64 * 64];
  __shared__ __align__(16) __hip_bfloat16 Ba[128 * 64];
  __shared__ __align__(16) __hip_bfloat16 Bg[128 * 64];
  const int tid = threadIdx.x;
  const int wv = tid >> 6, ln = tid & 63;
  const int hi = ln >> 4, lo = ln & 15;
  const int lo7 = lo & 7;
  const int gx = gridDim.x;
  const int nwg = gx * gridDim.y;
  const int t = blockIdx.y * gx + blockIdx.x;
  const int w = (t & 7) * (nwg >> 3) + (t >> 3);
  const int n0 = (w & (gx - 1)) * 64;
  const int m0 = (w / gx) * 128;
  const int wr = wv >> 1, wc = wv & 1;
  const int srow = ln >> 3;
  const int scolz = (((ln & 7) ^ srow) << 3);

  f32x4 acca[2][4] = {}, accg[2][4] = {};

  for (int k0 = 0; k0 < K; k0 += 64) {
    __syncthreads();
#pragma unroll
    for (int i = 0; i < 2; ++i) {
      const int grp = i * 4 + wv;
      gld16(A + (size_t)(n0 + grp * 8 + srow) * K + k0 + scolz, As + grp * 512);
    }
#pragma unroll
    for (int i = 0; i < 4; ++i) {
      const int grp = i * 4 + wv;
      gld16(W + (size_t)(m0 + grp * 8 + srow) * K + k0 + scolz, Ba + grp * 512);
      gld16(W + (size_t)(512 + m0 + grp * 8 + srow) * K + k0 + scolz, Bg + grp * 512);
    }
    __syncthreads();
#pragma unroll
    for (int kk2 = 0; kk2 < 2; ++kk2) {
      const int g0 = ((kk2 * 4 + hi) ^ lo7) << 3;
      bf16x8 af[2], ba[4], bg[4];
#pragma unroll
      for (int r = 0; r < 2; ++r)
        af[r] = *reinterpret_cast<const bf16x8*>(As + (wr * 32 + r * 16 + lo) * 64 + g0);
#pragma unroll
      for (int c = 0; c < 4; ++c) {
        ba[c] = *reinterpret_cast<const bf16x8*>(Ba + (wc * 64 + c * 16 + lo) * 64 + g0);
        bg[c] = *reinterpret_cast<const bf16x8*>(Bg + (wc * 64 + c * 16 + lo) * 64 + g0);
      }
#pragma unroll
      for (int r = 0; r < 2; ++r)
#pragma unroll
        for (int c = 0; c < 4; ++c) {
          acca[r][c] = __builtin_amdgcn_mfma_f32_16x16x32_bf16(af[r], ba[c], acca[r][c], 0, 0, 0);
          accg[r][c] = __builtin_amdgcn_mfma_f32_16x16x32_bf16(af[r], bg[c], accg[r][c], 0, 0, 0);
        }
    }
  }

#pragma unroll
  for (int r = 0; r < 2; ++r) {
#pragma unroll
    for (int c = 0; c < 4; ++c) {
      const int m = m0 + wc * 64 + c * 16 + lo;
      const float bva = bfp2f(bias + m);
      const float bvg = bfp2f(bias + 512 + m);
#pragma unroll
      for (int j = 0; j < 4; ++j) {
        const int n = n0 + wr * 32 + r * 16 + hi * 4 + j;
        const float a = acca[r][c][j] + bva;
        const float g = accg[r][c][j] + bvg;
        outb[(size_t)n * 512 + m] = __float2bfloat16(a / (1.f + __expf(-g)));
      }
    }
  }
}

// ---------------- MFMA flash attention v6.1: 3 blocks/CU (G1 occupancy) ----------
// LDS 40 KB -> 4 blocks/CU fit; (256,3) raises co-residency 2->3 (VGPR cap 170,
// footprint ~140 -> no spill). Latency/arbitration-bound per counters.
__global__ __launch_bounds__(256, 3) void attn_kernel(const __hip_bfloat16* __restrict__ qkv,
                                                      const __hip_bfloat16* __restrict__ vT,
                                                      __hip_bfloat16* __restrict__ ctx) {
  __shared__ __align__(16) short Ks[2][64 * 64];
  __shared__ __align__(16) short Vs[2][64 * 64];
  __shared__ __align__(16) short P[4][16][64];
  const int tid = threadIdx.x;
  const int wv = tid >> 6, ln = tid & 63;
  const int hi = ln >> 4, lo = ln & 15;
  const int lo7 = lo & 7;
  const int blk = ((blockIdx.x & 7) << 6) | (blockIdx.x >> 3);
  const int qt = blk & 7, h = (blk >> 3) & 7, b = blk >> 6;
  const int q0 = qt * 128 + wv * 16;   // tile A rows; tile B = q0 + 64

  const int srow8 = ln >> 3;
  const int gsrc = (ln & 7) ^ srow8;

  bf16x8 aq0a, aq1a, aq0b, aq1b;
  {
    const __hip_bfloat16* qpa = qkv + (size_t)(b * SEQ + q0 + lo) * 1536 + h * 64 + hi * 8;
    const __hip_bfloat16* qpb = qpa + (size_t)64 * 1536;
    bf16x8 r0 = *reinterpret_cast<const bf16x8*>(qpa);
    bf16x8 r1 = *reinterpret_cast<const bf16x8*>(qpa + 32);
    bf16x8 r2 = *reinterpret_cast<const bf16x8*>(qpb);
    bf16x8 r3 = *reinterpret_cast<const bf16x8*>(qpb + 32);
#pragma unroll
    for (int j = 0; j < 8; ++j) {
      aq0a[j] = f2bfs(bfs2f(r0[j]) * 0.125f);
      aq1a[j] = f2bfs(bfs2f(r1[j]) * 0.125f);
      aq0b[j] = f2bfs(bfs2f(r2[j]) * 0.125f);
      aq1b[j] = f2bfs(bfs2f(r3[j]) * 0.125f);
    }
  }

  const __hip_bfloat16* kbase = qkv + 512 + h * 64 + (size_t)b * SEQ * 1536;
  const __hip_bfloat16* vbase = vT + (size_t)(b * NH + h) * 64 * 1024;

  f32x4 oaccA[4] = {}, oaccB[4] = {};
  float lrowA[4] = {0.f, 0.f, 0.f, 0.f};
  float lrowB[4] = {0.f, 0.f, 0.f, 0.f};

#pragma unroll
  for (int c = 0; c < 2; ++c) {
    const int r = c * 32 + wv * 8 + srow8;
    gld16(kbase + (size_t)r * 1536 + gsrc * 8, &Ks[0][(c * 32 + wv * 8) * 64]);
    gld16(vbase + (size_t)r * 1024 + gsrc * 8, &Vs[0][(c * 32 + wv * 8) * 64]);
  }
  __syncthreads();

  int cb = 0;
  for (int kt = 0; kt < 16; ++kt) {
    if (kt < 15) {
      const int kb2 = (kt + 1) * 64;
#pragma unroll
      for (int c = 0; c < 2; ++c) {
        const int r = c * 32 + wv * 8 + srow8;
        gld16(kbase + (size_t)(kb2 + r) * 1536 + gsrc * 8,
              &Ks[cb ^ 1][(c * 32 + wv * 8) * 64]);
        gld16(vbase + (size_t)r * 1024 + kb2 + gsrc * 8,
              &Vs[cb ^ 1][(c * 32 + wv * 8) * 64]);
      }
    }

    bf16x8 bk0[4], bk1[4];
#pragma unroll
    for (int nt = 0; nt < 4; ++nt) {
      const short* kr = &Ks[cb][(nt * 16 + lo) * 64];
      bk0[nt] = *reinterpret_cast<const bf16x8*>(kr + ((hi ^ lo7) << 3));
      bk1[nt] = *reinterpret_cast<const bf16x8*>(kr + (((hi + 4) ^ lo7) << 3));
    }
    f32x4 scA[4] = {}, scB[4] = {};
#pragma unroll
    for (int nt = 0; nt < 4; ++nt) {
      scA[nt] = __builtin_amdgcn_mfma_f32_16x16x32_bf16(aq0a, bk0[nt], scA[nt], 0, 0, 0);
      scA[nt] = __builtin_amdgcn_mfma_f32_16x16x32_bf16(aq1a, bk1[nt], scA[nt], 0, 0, 0);
      scB[nt] = __builtin_amdgcn_mfma_f32_16x16x32_bf16(aq0b, bk0[nt], scB[nt], 0, 0, 0);
      scB[nt] = __builtin_amdgcn_mfma_f32_16x16x32_bf16(aq1b, bk1[nt], scB[nt], 0, 0, 0);
    }

    bf16x8 bv0[4], bv1[4];
#pragma unroll
    for (int dt = 0; dt < 4; ++dt) {
      const short* vr = &Vs[cb][(dt * 16 + lo) * 64];
      bv0[dt] = *reinterpret_cast<const bf16x8*>(vr + ((hi ^ lo7) << 3));
      bv1[dt] = *reinterpret_cast<const bf16x8*>(vr + (((hi + 4) ^ lo7) << 3));
    }

#pragma unroll
    for (int j = 0; j < 4; ++j) {
      const int prow = hi * 4 + j;
      const int pswz = (prow & 7) << 3;
#pragma unroll
      for (int nt = 0; nt < 4; ++nt) {
        const float p = __expf(scA[nt][j]);
        P[wv][prow][(nt * 16 + lo) ^ pswz] = f2bfs(p);
        lrowA[j] += p;
      }
    }
    asm volatile("" ::: "memory");
    {
      const short* pr = &P[wv][lo][0];
      bf16x8 ap0 = *reinterpret_cast<const bf16x8*>(pr + ((hi ^ lo7) << 3));
      bf16x8 ap1 = *reinterpret_cast<const bf16x8*>(pr + (((hi + 4) ^ lo7) << 3));
#pragma unroll
      for (int dt = 0; dt < 4; ++dt) {
        oaccA[dt] = __builtin_amdgcn_mfma_f32_16x16x32_bf16(ap0, bv0[dt], oaccA[dt], 0, 0, 0);
        oaccA[dt] = __builtin_amdgcn_mfma_f32_16x16x32_bf16(ap1, bv1[dt], oaccA[dt], 0, 0, 0);
      }
    }
    asm volatile("" ::: "memory");

#pragma unroll
    for (int j = 0; j < 4; ++j) {
      const int prow = hi * 4 + j;
      const int pswz = (prow & 7) << 3;
#pragma unroll
      for (int nt = 0; nt < 4; ++nt) {
        const float p = __expf(scB[nt][j]);
        P[wv][prow][(nt * 16 + lo) ^ pswz] = f2bfs(p);
        lrowB[j] += p;
      }
    }
    asm volatile("" ::: "memory");
    {
      const short* pr = &P[wv][lo][0];
      bf16x8 ap0 = *reinterpret_cast<const bf16x8*>(pr + ((hi ^ lo7) << 3));
      bf16x8 ap1 = *reinterpret_cast<const bf16x8*>(pr + (((hi + 4) ^ lo7) << 3));
#pragma unroll
      for (int dt = 0; dt < 4; ++dt) {
        oaccB[dt] = __builtin_amdgcn_mfma_f32_16x16x32_bf16(ap0, bv0[dt], oaccB[dt], 0, 0, 0);
        oaccB[dt] = __builtin_amdgcn_mfma_f32_16x16x32_bf16(ap1, bv1[dt], oaccB[dt], 0, 0, 0);
      }
    }
    __syncthreads();
    cb ^= 1;
  }

#pragma unroll
  for (int j = 0; j < 4; ++j) {
    float sa = lrowA[j], sb = lrowB[j];
    sa += __shfl_xor(sa, 1); sb += __shfl_xor(sb, 1);
    sa += __shfl_xor(sa, 2); sb += __shfl_xor(sb, 2);
    sa += __shfl_xor(sa, 4); sb += __shfl_xor(sb, 4);
    sa += __shfl_xor(sa, 8); sb += __shfl_xor(sb, 8);
    lrowA[j] = sa; lrowB[j] = sb;
  }

#pragma unroll
  for (int dt = 0; dt < 4; ++dt)
#pragma unroll
    for (int j = 0; j < 4; ++j) {
      const int d = h * 64 + dt * 16 + lo;
      const int na = b * SEQ + q0 + hi * 4 + j;
      ctx[(size_t)na * 512 + d] = __float2bfloat16(oaccA[dt][j] / lrowA[j]);
      const int nb = na + 64;
      ctx[(size_t)nb * 512 + d] = __float2bfloat16(oaccB[dt][j] / lrowB[j]);
    }
}

// ---------------- depthwise conv K=31 + BN + SiLU, bf16 in, 8 ch/thread ----------
__global__ __launch_bounds__(256) void dwconv8_kernel(const __hip_bfloat16* __restrict__ cin,
                                                      const __hip_bfloat16* __restrict__ wkT,
                                                      const __hip_bfloat16* __restrict__ cb,
                                                      const __hip_bfloat16* __restrict__ bng,
                                                      const __hip_bfloat16* __restrict__ bnb,
                                                      const __hip_bfloat16* __restrict__ bnm,
                                                      const __hip_bfloat16* __restrict__ bnv,
                                                      __hip_bfloat16* __restrict__ outp) {
  const int i = blockIdx.x * 256 + threadIdx.x;
  const int c8 = i & 63;
  const int n = i >> 6;
  const int t = n & 1023;
  const int base = n - t;
  const int co = c8 * 8;

  float acc[8];
  {
    bf16x8 bv = *reinterpret_cast<const bf16x8*>(cb + co);
#pragma unroll
    for (int j = 0; j < 8; ++j) acc[j] = bfs2f(bv[j]);
  }
  const int k0 = (t >= 15) ? 0 : (15 - t);
  const int k1 = (t <= SEQ - 16) ? 31 : (SEQ - 1 - t + 16);
  const short* cin_s = reinterpret_cast<const short*>(cin);
  const short* wk_s = reinterpret_cast<const short*>(wkT);
  for (int k = k0; k < k1; ++k) {
    const int ts = t + k - 15;
    bf16x8 xv = *reinterpret_cast<const bf16x8*>(cin_s + (((size_t)(base + ts)) << 9) + co);
    bf16x8 wv = *reinterpret_cast<const bf16x8*>(wk_s + k * 512 + co);
#pragma unroll
    for (int j = 0; j < 8; ++j) acc[j] += bfs2f(xv[j]) * bfs2f(wv[j]);
  }
  bf16x8 g = *reinterpret_cast<const bf16x8*>(bng + co);
  bf16x8 bb = *reinterpret_cast<const bf16x8*>(bnb + co);
  bf16x8 bm = *reinterpret_cast<const bf16x8*>(bnm + co);
  bf16x8 bvv = *reinterpret_cast<const bf16x8*>(bnv + co);
  bf16x8 ov;
#pragma unroll
  for (int j = 0; j < 8; ++j) {
    const float scl = bfs2f(g[j]) * rsqrtf(bfs2f(bvv[j]) + 1e-5f);
    float v = (acc[j] - bfs2f(bm[j])) * scl + bfs2f(bb[j]);
    v = v / (1.f + __expf(-v));
    ov[j] = f2bfs(v);
  }
  *reinterpret_cast<bf16x8*>(reinterpret_cast<short*>(outp) + ((size_t)n << 9) + co) = ov;
}

extern "C" void kernel_launch(void* const* d_in, const int* in_sizes, int n_in,
                              void* d_out, int out_size, void* d_ws, size_t ws_size,
                              hipStream_t stream) {
  float* out = (float*)d_out;  // confirmed: f32 in / f32 out
  if (ws_size < ((size_t)80 << 20)) {
    ws_bad_kernel<<<1, 64, 0, stream>>>(out);  // sentinel 5000
    return;
  }

  const float* x = (const float*)d_in[0];

  char* ws = (char*)d_ws;
  __hip_bfloat16* xsb = (__hip_bfloat16*)ws;                             // 0-8 MB bf16 stream
  __hip_bfloat16* t0 = (__hip_bfloat16*)(ws + ((size_t)16 << 20));       // 16-24 MB
  __hip_bfloat16* t1 = (__hip_bfloat16*)(ws + ((size_t)24 << 20));       // 24-48 MB
  __hip_bfloat16* t2 = (__hip_bfloat16*)(ws + ((size_t)56 << 20));       // 56-64 MB
  __hip_bfloat16* wc = (__hip_bfloat16*)(ws + ((size_t)64 << 20));       // 64-76 MB
  __hip_bfloat16* vT = t1 + (size_t)NTOK * 1536;                         // 48-56 MB

  __hip_bfloat16* wc_ff1_w1 = wc + 0;
  __hip_bfloat16* wc_ff1_w2 = wc + 1048576;
  __hip_bfloat16* wc_qkv_w  = wc + 2097152;
  __hip_bfloat16* wc_out_w  = wc + 2883584;
  __hip_bfloat16* wc_pw1_w  = wc + 3145728;
  __hip_bfloat16* wc_pw2_w  = wc + 3670016;
  __hip_bfloat16* wc_ff2_w1 = wc + 3932160;
  __hip_bfloat16* wc_ff2_w2 = wc + 4980736;
  __hip_bfloat16* wc_dwT    = wc + 6029312;      // [31][512] bf16 transposed
  __hip_bfloat16* sm        = wc + 6045184;
  __hip_bfloat16* c_ln1_g = sm + 0,     *c_ln1_b = sm + 512,   *c_ff1_b1 = sm + 1024;
  __hip_bfloat16* c_ff1_b2 = sm + 3072, *c_lna_g = sm + 3584,  *c_lna_b = sm + 4096;
  __hip_bfloat16* c_qkv_b = sm + 4608,  *c_out_b = sm + 6144,  *c_lnc_g = sm + 6656;
  __hip_bfloat16* c_lnc_b = sm + 7168,  *c_pw1_b = sm + 7680,  *c_dw_b = sm + 8704;
  __hip_bfloat16* c_bn_g = sm + 9216,   *c_bn_b = sm + 9728,   *c_bn_m = sm + 10240;
  __hip_bfloat16* c_bn_v = sm + 10752,  *c_pw2_b = sm + 11264, *c_ln2_g = sm + 11776;
  __hip_bfloat16* c_ln2_b = sm + 12288, *c_ff2_b1 = sm + 12800, *c_ff2_b2 = sm + 14848;
  __hip_bfloat16* c_lnf_g = sm + 15360, *c_lnf_b = sm + 15872;

  // --- input normalization (f32 world) ---
  {
    WPack wp;
    wp.s[0] = {(const float*)d_in[3],  0,      131072};  // ff1_w1
    wp.s[1] = {(const float*)d_in[5],  131072, 131072};  // ff1_w2
    wp.s[2] = {(const float*)d_in[9],  262144, 98304};   // qkv_w
    wp.s[3] = {(const float*)d_in[11], 360448, 32768};   // out_w
    wp.s[4] = {(const float*)d_in[15], 393216, 65536};   // pw1_w
    wp.s[5] = {(const float*)d_in[23], 458752, 32768};   // pw2_w
    wp.s[6] = {(const float*)d_in[27], 491520, 131072};  // ff2_w1
    wp.s[7] = {(const float*)d_in[29], 622592, 131072};  // ff2_w2
    cast_wall_kernel<<<2944, 256, 0, stream>>>(wp, wc);
  }
  cast_dww_kernel<<<1, 256, 0, stream>>>((const float*)d_in[17], wc_dwT);
  PtrPack pk;
  const int small_idx[23] = {1, 2, 4, 6, 7, 8, 10, 12, 13, 14, 16, 18,
                             19, 20, 21, 22, 24, 25, 26, 28, 30, 31, 32};
  for (int t = 0; t < 23; ++t) pk.p[t] = d_in[small_idx[t]];
  cast_small_kernel<<<1, 256, 0, stream>>>(pk, sm);

  // --- FF1 (half-scale): xsb = 1.5*x + 0.5*(silu(ln(x)@w1)@w2 + b2) ---
  ln_kernel<<<2048, 256, 0, stream>>>(x, c_ln1_g, c_ln1_b, t0);
  gemm_bt<1><<<dim3(64, 16), 256, 0, stream>>>(t0, wc_ff1_w1, c_ff1_b1, t1, nullptr, 512, 2048);
  gemm64_resid<1><<<dim3(128, 4), 256, 0, stream>>>(t1, wc_ff1_w2, c_ff1_b2, x, xsb, 2048, 1.5f, 0.5f);

  // --- Attention (qkv GEMM with fused V-transpose; MFMA flash v6.1) ---
  lnb_kernel<<<2048, 256, 0, stream>>>(xsb, c_lna_g, c_lna_b, t0);
  gemm_bt<3><<<dim3(64, 12), 256, 0, stream>>>(t0, wc_qkv_w, c_qkv_b, t1, vT, 512, 1536);
  attn_kernel<<<512, 256, 0, stream>>>(t1, vT, t2);
  gemm64_resid<0><<<dim3(128, 4), 256, 0, stream>>>(t2, wc_out_w, c_out_b, xsb, xsb, 512, 1.0f, 1.0f);

  // --- Conv module (pw1 GEMM with fused GLU) ---
  lnb_kernel<<<2048, 256, 0, stream>>>(xsb, c_lnc_g, c_lnc_b, t0);
  gemm_glu<<<dim3(128, 4), 256, 0, stream>>>(t0, wc_pw1_w, c_pw1_b, t2, 512);
  dwconv8_kernel<<<2048, 256, 0, stream>>>(t2, wc_dwT, c_dw_b, c_bn_g, c_bn_b, c_bn_m, c_bn_v, t0);
  gemm64_resid<0><<<dim3(128, 4), 256, 0, stream>>>(t0, wc_pw2_w, c_pw2_b, xsb, xsb, 512, 2.0f, 1.0f);

  // --- FF2 (half-scale) ---
  lnb_kernel<<<2048, 256, 0, stream>>>(xsb, c_ln2_g, c_ln2_b, t0);
  gemm_bt<1><<<dim3(64, 16), 256, 0, stream>>>(t0, wc_ff2_w1, c_ff2_b1, t1, nullptr, 512, 2048);
  gemm64_resid<0><<<dim3(128, 4), 256, 0, stream>>>(t1, wc_ff2_w2, c_ff2_b2, xsb, xsb, 2048, 1.5f, 0.5f);

  // --- Final LN -> FP32 out ---
  lnf_kernel<<<2048, 256, 0, stream>>>(xsb, c_lnf_g, c_lnf_b, out);
}